// Round 3
// baseline (384.259 us; speedup 1.0000x reference)
//
#include <hip/hip_runtime.h>
#include <cstdint>

typedef long long i64;

// ---------------------------------------------------------------------------
// FraudGNN: 2-layer GraphSAGE (mean aggr), N=100K, E=1.6M, d 64->64->2, fp32.
// Rewrite: lin(mean(x)) == mean(lin(x))  -> transform first, aggregate after.
//   XL = x@W1l^T ; XR = x@W1r^T + b1l
//   h  = relu(meanagg(XL) + XR)            (registers only, never stored)
//   HL = h@W2l^T ; HR = h@W2r^T + b2l      (fused into the aggregation kernel)
//   out = meanagg(HL) + HR                 (2-dim gather, L2-resident)
// CSR built once (shared by both layers).
// ---------------------------------------------------------------------------

// --- edge dtype probe: harness doc says int32, reference says int64. Detect.
__global__ __launch_bounds__(256) void k_detect(const int* __restrict__ e, int* __restrict__ flag) {
  __shared__ int nz;
  if (threadIdx.x == 0) nz = 0;
  __syncthreads();
  // If data is int64 (values < 2^31, nonneg), every odd 32-bit word is 0.
  if (e[2 * threadIdx.x + 1] != 0) nz = 1;   // benign race, all write 1
  __syncthreads();
  if (threadIdx.x == 0) *flag = (nz == 0) ? 1 : 0;  // 1 => int64 layout
}

__device__ __forceinline__ int edge_at(const void* eidx, int is64, size_t i) {
  return is64 ? (int)((const i64*)eidx)[i] : ((const int*)eidx)[i];
}

// --- CSR build -------------------------------------------------------------
__global__ __launch_bounds__(256) void k_hist(const void* __restrict__ eidx, const int* __restrict__ flag,
                                              int* __restrict__ deg, int E) {
  int e = blockIdx.x * 256 + threadIdx.x;
  if (e >= E) return;
  int is64 = *flag;
  int d = edge_at(eidx, is64, (size_t)E + e);
  atomicAdd(&deg[d], 1);
}

// exclusive scan of deg -> row_ptr ; 1024 elems per block (256 thr x int4)
__global__ __launch_bounds__(256) void k_scan_block(const int* __restrict__ deg, int* __restrict__ rp,
                                                    int* __restrict__ bsums, int n) {
  __shared__ int lds[256];
  int t = threadIdx.x;
  int base = blockIdx.x * 1024 + t * 4;
  int4 v = make_int4(0, 0, 0, 0);
  if (base < n) v = *(const int4*)(deg + base);   // n % 4 == 0 by construction
  int s1 = v.x + v.y, s2 = s1 + v.z, tot = s2 + v.w;
  lds[t] = tot;
  __syncthreads();
  for (int off = 1; off < 256; off <<= 1) {
    int a = (t >= off) ? lds[t - off] : 0;
    __syncthreads();
    lds[t] += a;
    __syncthreads();
  }
  int excl = lds[t] - tot;
  if (base < n) {
    int4 o = make_int4(excl, excl + v.x, excl + s1, excl + s2);
    *(int4*)(rp + base) = o;
  }
  if (t == 255) bsums[blockIdx.x] = lds[255];
}

__global__ __launch_bounds__(128) void k_scan_sums(const int* __restrict__ bsums, int* __restrict__ boffs, int nb) {
  __shared__ int lds[128];
  int t = threadIdx.x;
  int own = (t < nb) ? bsums[t] : 0;
  lds[t] = own;
  __syncthreads();
  for (int off = 1; off < 128; off <<= 1) {
    int a = (t >= off) ? lds[t - off] : 0;
    __syncthreads();
    lds[t] += a;
    __syncthreads();
  }
  if (t < nb) boffs[t] = lds[t] - own;  // exclusive
}

__global__ __launch_bounds__(256) void k_scan_add(int* __restrict__ rp, int* __restrict__ cursor,
                                                  const int* __restrict__ boffs, int n, int E) {
  int base = blockIdx.x * 1024 + threadIdx.x * 4;
  int off = boffs[blockIdx.x];
  if (base < n) {
    int4 v = *(const int4*)(rp + base);
    v.x += off; v.y += off; v.z += off; v.w += off;
    *(int4*)(rp + base) = v;
    *(int4*)(cursor + base) = v;
  }
  if (blockIdx.x == 0 && threadIdx.x == 0) rp[n] = E;
}

__global__ __launch_bounds__(256) void k_scatter(const void* __restrict__ eidx, const int* __restrict__ flag,
                                                 int* __restrict__ cursor, int* __restrict__ csr_src, int E) {
  int e = blockIdx.x * 256 + threadIdx.x;
  if (e >= E) return;
  int is64 = *flag;
  int s = edge_at(eidx, is64, (size_t)e);
  int d = edge_at(eidx, is64, (size_t)E + e);
  int p = atomicAdd(&cursor[d], 1);
  csr_src[p] = s;
}

// --- GEMM1: XL = x@W1l^T, XR = x@W1r^T + b1l  (64x64 tile, LDS-staged) -----
__global__ __launch_bounds__(256) void k_gemm1(const float* __restrict__ x,
                                               const float* __restrict__ Wl, const float* __restrict__ bl,
                                               const float* __restrict__ Wr,
                                               float* __restrict__ XL, float* __restrict__ XR, int n_nodes) {
  // stride 68 floats (272B = 17*16B): float4-aligned, k-major reads land 2-way
  // on banks (free per m136).
  __shared__ float sWl[64 * 68];
  __shared__ float sWr[64 * 68];
  __shared__ float sX[64 * 68];
  int tid = threadIdx.x;
  int base = blockIdx.x * 64;

#pragma unroll
  for (int r = 0; r < 4; ++r) {              // weights: 64f x 16 float4
    int idx = tid + 256 * r;
    int f = idx >> 4, c4 = idx & 15;
    float4 wl = *(const float4*)(Wl + f * 64 + c4 * 4);
    float4 wr = *(const float4*)(Wr + f * 64 + c4 * 4);
    sWl[(c4 * 4 + 0) * 68 + f] = wl.x; sWl[(c4 * 4 + 1) * 68 + f] = wl.y;
    sWl[(c4 * 4 + 2) * 68 + f] = wl.z; sWl[(c4 * 4 + 3) * 68 + f] = wl.w;
    sWr[(c4 * 4 + 0) * 68 + f] = wr.x; sWr[(c4 * 4 + 1) * 68 + f] = wr.y;
    sWr[(c4 * 4 + 2) * 68 + f] = wr.z; sWr[(c4 * 4 + 3) * 68 + f] = wr.w;
  }
#pragma unroll
  for (int r = 0; r < 4; ++r) {              // x tile: 64n x 16 float4
    int idx = tid + 256 * r;
    int nn = idx >> 4, c4 = idx & 15;
    int node = base + nn;
    float4 xv = make_float4(0.f, 0.f, 0.f, 0.f);
    if (node < n_nodes) xv = *(const float4*)(x + (size_t)node * 64 + c4 * 4);
    sX[(c4 * 4 + 0) * 68 + nn] = xv.x; sX[(c4 * 4 + 1) * 68 + nn] = xv.y;
    sX[(c4 * 4 + 2) * 68 + nn] = xv.z; sX[(c4 * 4 + 3) * 68 + nn] = xv.w;
  }
  __syncthreads();

  int f0 = (tid & 15) * 4, n0 = (tid >> 4) * 4;
  float accL[4][4] = {{0}}, accR[4][4] = {{0}};
#pragma unroll 8
  for (int k = 0; k < 64; ++k) {
    float4 xv = *(const float4*)&sX[k * 68 + n0];
    float4 wl = *(const float4*)&sWl[k * 68 + f0];
    float4 wr = *(const float4*)&sWr[k * 68 + f0];
    float xn[4] = {xv.x, xv.y, xv.z, xv.w};
    float wlf[4] = {wl.x, wl.y, wl.z, wl.w};
    float wrf[4] = {wr.x, wr.y, wr.z, wr.w};
#pragma unroll
    for (int a = 0; a < 4; ++a)
#pragma unroll
      for (int b = 0; b < 4; ++b) {
        accL[a][b] += xn[a] * wlf[b];
        accR[a][b] += xn[a] * wrf[b];
      }
  }

  float4 blv = *(const float4*)(bl + f0);
#pragma unroll
  for (int a = 0; a < 4; ++a) {
    int node = base + n0 + a;
    if (node >= n_nodes) continue;
    float4 ol = make_float4(accL[a][0], accL[a][1], accL[a][2], accL[a][3]);
    float4 orr = make_float4(accR[a][0] + blv.x, accR[a][1] + blv.y,
                             accR[a][2] + blv.z, accR[a][3] + blv.w);
    *(float4*)(XL + (size_t)node * 64 + f0) = ol;
    *(float4*)(XR + (size_t)node * 64 + f0) = orr;
  }
}

// --- AGG1 + GEMM2 fused ----------------------------------------------------
// h = relu(mean_j XL[j] + XR) computed in registers (16 lanes x float4/node),
// then HL = h@W2l^T, HR = h@W2r^T + b2l via in-group shfl_xor dot-reduce.
// h is never written to global memory. Gather unrolled 4x for MLP (L3-latency
// bound: 410MB logical reads from a 25.6MB L3-resident table).
__global__ __launch_bounds__(256) void k_agg1g2(const int* __restrict__ rp, const int* __restrict__ csr_src,
                                                const float* __restrict__ XL, const float* __restrict__ XR,
                                                const float* __restrict__ W2l, const float* __restrict__ b2l,
                                                const float* __restrict__ W2r,
                                                float* __restrict__ HL, float* __restrict__ HR,
                                                int n_nodes) {
  int wave = threadIdx.x >> 6, lane = threadIdx.x & 63;
  int g = lane >> 4, c = lane & 15;
  int n = (blockIdx.x * 4 + wave) * 4 + g;
  if (n >= n_nodes) return;

  // per-lane slices of the 2x64 projection weights (L1-broadcast, 16B each)
  float4 wl0 = *(const float4*)(W2l + c * 4);
  float4 wl1 = *(const float4*)(W2l + 64 + c * 4);
  float4 wr0 = *(const float4*)(W2r + c * 4);
  float4 wr1 = *(const float4*)(W2r + 64 + c * 4);
  // hoisted self-row read: overlaps the gather below
  float4 xr = *(const float4*)(XR + (size_t)n * 64 + c * 4);

  int start = rp[n], end = rp[n + 1];
  float4 a0 = make_float4(0.f, 0.f, 0.f, 0.f);
  float4 a1 = make_float4(0.f, 0.f, 0.f, 0.f);
  float4 a2 = make_float4(0.f, 0.f, 0.f, 0.f);
  float4 a3 = make_float4(0.f, 0.f, 0.f, 0.f);
  int e = start;
  for (; e + 3 < end; e += 4) {               // unroll-4: 4 outstanding 256B reads
    int s0 = csr_src[e], s1 = csr_src[e + 1], s2 = csr_src[e + 2], s3 = csr_src[e + 3];
    float4 v0 = *(const float4*)(XL + (size_t)s0 * 64 + c * 4);
    float4 v1 = *(const float4*)(XL + (size_t)s1 * 64 + c * 4);
    float4 v2 = *(const float4*)(XL + (size_t)s2 * 64 + c * 4);
    float4 v3 = *(const float4*)(XL + (size_t)s3 * 64 + c * 4);
    a0.x += v0.x; a0.y += v0.y; a0.z += v0.z; a0.w += v0.w;
    a1.x += v1.x; a1.y += v1.y; a1.z += v1.z; a1.w += v1.w;
    a2.x += v2.x; a2.y += v2.y; a2.z += v2.z; a2.w += v2.w;
    a3.x += v3.x; a3.y += v3.y; a3.z += v3.z; a3.w += v3.w;
  }
  if (e + 1 < end) {
    int s0 = csr_src[e], s1 = csr_src[e + 1];
    float4 v0 = *(const float4*)(XL + (size_t)s0 * 64 + c * 4);
    float4 v1 = *(const float4*)(XL + (size_t)s1 * 64 + c * 4);
    a0.x += v0.x; a0.y += v0.y; a0.z += v0.z; a0.w += v0.w;
    a1.x += v1.x; a1.y += v1.y; a1.z += v1.z; a1.w += v1.w;
    e += 2;
  }
  if (e < end) {
    int s0 = csr_src[e];
    float4 v0 = *(const float4*)(XL + (size_t)s0 * 64 + c * 4);
    a0.x += v0.x; a0.y += v0.y; a0.z += v0.z; a0.w += v0.w;
  }
  float inv = 1.0f / fmaxf((float)(end - start), 1.0f);
  float4 h;
  h.x = fmaxf((a0.x + a1.x + a2.x + a3.x) * inv + xr.x, 0.f);
  h.y = fmaxf((a0.y + a1.y + a2.y + a3.y) * inv + xr.y, 0.f);
  h.z = fmaxf((a0.z + a1.z + a2.z + a3.z) * inv + xr.z, 0.f);
  h.w = fmaxf((a0.w + a1.w + a2.w + a3.w) * inv + xr.w, 0.f);

  // fused 64->2 projections: per-lane dot, butterfly-reduce over 16 lanes
  float p0 = h.x * wl0.x + h.y * wl0.y + h.z * wl0.z + h.w * wl0.w;
  float p1 = h.x * wl1.x + h.y * wl1.y + h.z * wl1.z + h.w * wl1.w;
  float q0 = h.x * wr0.x + h.y * wr0.y + h.z * wr0.z + h.w * wr0.w;
  float q1 = h.x * wr1.x + h.y * wr1.y + h.z * wr1.z + h.w * wr1.w;
#pragma unroll
  for (int off = 1; off < 16; off <<= 1) {
    p0 += __shfl_xor(p0, off, 16);
    p1 += __shfl_xor(p1, off, 16);
    q0 += __shfl_xor(q0, off, 16);
    q1 += __shfl_xor(q1, off, 16);
  }
  if (c == 0) {
    *(float2*)(HL + (size_t)n * 2) = make_float2(p0, p1);
    *(float2*)(HR + (size_t)n * 2) = make_float2(q0 + b2l[0], q1 + b2l[1]);
  }
}

// --- AGG2: out = mean_j HL[j] + HR  (thread per node, 2-dim features) ------
__global__ __launch_bounds__(256) void k_agg2(const int* __restrict__ rp, const int* __restrict__ csr_src,
                                              const float* __restrict__ HL, const float* __restrict__ HR,
                                              float* __restrict__ out, int n_nodes) {
  int n = blockIdx.x * 256 + threadIdx.x;
  if (n >= n_nodes) return;
  int start = rp[n], end = rp[n + 1];
  float s0 = 0.f, s1 = 0.f;
  int e = start;
  for (; e + 1 < end; e += 2) {
    int sa = csr_src[e], sb = csr_src[e + 1];
    float2 va = *(const float2*)(HL + (size_t)sa * 2);
    float2 vb = *(const float2*)(HL + (size_t)sb * 2);
    s0 += va.x + vb.x; s1 += va.y + vb.y;
  }
  if (e < end) {
    int sa = csr_src[e];
    float2 va = *(const float2*)(HL + (size_t)sa * 2);
    s0 += va.x; s1 += va.y;
  }
  float inv = 1.0f / fmaxf((float)(end - start), 1.0f);
  float2 hr = *(const float2*)(HR + (size_t)n * 2);
  out[n * 2 + 0] = s0 * inv + hr.x;
  out[n * 2 + 1] = s1 * inv + hr.y;
}

// ---------------------------------------------------------------------------
extern "C" void kernel_launch(void* const* d_in, const int* in_sizes, int n_in,
                              void* d_out, int out_size, void* d_ws, size_t ws_size,
                              hipStream_t stream) {
  const float* x   = (const float*)d_in[0];
  const void*  eix = d_in[1];
  const float* W1l = (const float*)d_in[2];
  const float* b1l = (const float*)d_in[3];
  const float* W1r = (const float*)d_in[4];
  const float* W2l = (const float*)d_in[5];
  const float* b2l = (const float*)d_in[6];
  const float* W2r = (const float*)d_in[7];
  float* out = (float*)d_out;

  const int N = in_sizes[0] / 64;       // 100000
  const int E = in_sizes[1] / 2;        // 1600000

  // workspace layout (256B-aligned chunks)
  char* base = (char*)d_ws;
  size_t off = 0;
  auto alloc = [&](size_t bytes) {
    char* p = base + off;
    off = (off + bytes + 255) & ~(size_t)255;
    return p;
  };
  int*   deg     = (int*)alloc((size_t)N * 4);
  int*   rp      = (int*)alloc((size_t)(N + 1) * 4);
  int*   cursor  = (int*)alloc((size_t)N * 4);
  int*   bsums   = (int*)alloc(1024);
  int*   boffs   = (int*)alloc(1024);
  int*   flag    = (int*)alloc(256);
  int*   csr_src = (int*)alloc((size_t)E * 4);
  float* XL      = (float*)alloc((size_t)N * 64 * 4);
  float* XR      = (float*)alloc((size_t)N * 64 * 4);
  float* HL      = (float*)alloc((size_t)N * 2 * 4);
  float* HR      = (float*)alloc((size_t)N * 2 * 4);
  (void)ws_size;

  const int nb_scan = (N + 1023) / 1024;          // 98
  const int nb_edge = (E + 255) / 256;            // 6250

  hipMemsetAsync(deg, 0, (size_t)N * 4, stream);
  k_detect<<<1, 256, 0, stream>>>((const int*)eix, flag);
  k_hist<<<nb_edge, 256, 0, stream>>>(eix, flag, deg, E);
  k_scan_block<<<nb_scan, 256, 0, stream>>>(deg, rp, bsums, N);
  k_scan_sums<<<1, 128, 0, stream>>>(bsums, boffs, nb_scan);
  k_scan_add<<<nb_scan, 256, 0, stream>>>(rp, cursor, boffs, N, E);
  k_scatter<<<nb_edge, 256, 0, stream>>>(eix, flag, cursor, csr_src, E);

  k_gemm1<<<(N + 63) / 64, 256, 0, stream>>>(x, W1l, b1l, W1r, XL, XR, N);
  k_agg1g2<<<(N + 15) / 16, 256, 0, stream>>>(rp, csr_src, XL, XR, W2l, b2l, W2r, HL, HR, N);
  k_agg2<<<(N + 255) / 256, 256, 0, stream>>>(rp, csr_src, HL, HR, out, N);
}

// Round 4
// 323.179 us; speedup vs baseline: 1.1890x; 1.1890x over previous
//
#include <hip/hip_runtime.h>
#include <cstdint>

typedef long long i64;

// ---------------------------------------------------------------------------
// FraudGNN: 2-layer GraphSAGE (mean aggr), N=100K, E=1.6M, d 64->64->2, fp32.
// Rewrite: lin(mean(x)) == mean(lin(x))  -> transform first, aggregate after.
//   XL = x@W1l^T ; XR = x@W1r^T + b1l
//   h  = relu(meanagg(XL) + XR)            (registers only, never stored)
//   HL = h@W2l^T ; HR = h@W2r^T + b2l      (fused into the aggregation kernel)
//   out = meanagg(HL) + HR                 (2-dim gather, L2-resident)
//
// CSR build: two-level bucketed counting sort. Round-3 profile showed the
// naive global scatter at 138us with 105MB HBM writes (16x write amp from
// random 4B stores + cross-XCD line sharing). Pass A appends (s,d) pairs in
// dense per-chunk runs into 256-node buckets; pass B gives each bucket's CSR
// region to exactly ONE workgroup (per-node cursors in LDS, single-writer
// global stores) -> write amp ~1.
// ---------------------------------------------------------------------------

#define BKT_SHIFT 8          // 256 nodes per bucket
#define BKT_MAX   512        // LDS array size (NB=391 for N=100000)
#define CHUNK     16384      // edges per pass-A workgroup

// --- edge dtype probe: harness doc says int32, reference says int64. Detect.
__global__ __launch_bounds__(256) void k_detect(const int* __restrict__ e, int* __restrict__ flag) {
  __shared__ int nz;
  if (threadIdx.x == 0) nz = 0;
  __syncthreads();
  // If data is int64 (values < 2^31, nonneg), every odd 32-bit word is 0.
  if (e[2 * threadIdx.x + 1] != 0) nz = 1;   // benign race, all write 1
  __syncthreads();
  if (threadIdx.x == 0) *flag = (nz == 0) ? 1 : 0;  // 1 => int64 layout
}

__device__ __forceinline__ int edge_at(const void* eidx, int is64, size_t i) {
  return is64 ? (int)((const i64*)eidx)[i] : ((const int*)eidx)[i];
}

// --- node-degree histogram + bucket histogram (LDS-staged) -----------------
__global__ __launch_bounds__(256) void k_hist(const void* __restrict__ eidx, const int* __restrict__ flag,
                                              int* __restrict__ deg, int* __restrict__ bhist, int E) {
  __shared__ int bh[BKT_MAX];
  for (int i = threadIdx.x; i < BKT_MAX; i += 256) bh[i] = 0;
  __syncthreads();
  int is64 = *flag;
  int base = blockIdx.x * 4096;
  int end = min(base + 4096, E);
  for (int e = base + threadIdx.x; e < end; e += 256) {
    int d = edge_at(eidx, is64, (size_t)E + e);
    atomicAdd(&deg[d], 1);
    atomicAdd(&bh[d >> BKT_SHIFT], 1);
  }
  __syncthreads();
  for (int i = threadIdx.x; i < BKT_MAX; i += 256)
    if (bh[i]) atomicAdd(&bhist[i], bh[i]);
}

// exclusive scan of deg -> row_ptr ; 1024 elems per block (256 thr x int4)
__global__ __launch_bounds__(256) void k_scan_block(const int* __restrict__ deg, int* __restrict__ rp,
                                                    int* __restrict__ bsums, int n) {
  __shared__ int lds[256];
  int t = threadIdx.x;
  int base = blockIdx.x * 1024 + t * 4;
  int4 v = make_int4(0, 0, 0, 0);
  if (base < n) v = *(const int4*)(deg + base);   // n % 4 == 0 by construction
  int s1 = v.x + v.y, s2 = s1 + v.z, tot = s2 + v.w;
  lds[t] = tot;
  __syncthreads();
  for (int off = 1; off < 256; off <<= 1) {
    int a = (t >= off) ? lds[t - off] : 0;
    __syncthreads();
    lds[t] += a;
    __syncthreads();
  }
  int excl = lds[t] - tot;
  if (base < n) {
    int4 o = make_int4(excl, excl + v.x, excl + s1, excl + s2);
    *(int4*)(rp + base) = o;
  }
  if (t == 255) bsums[blockIdx.x] = lds[255];
}

__global__ __launch_bounds__(128) void k_scan_sums(const int* __restrict__ bsums, int* __restrict__ boffs, int nb) {
  __shared__ int lds[128];
  int t = threadIdx.x;
  int own = (t < nb) ? bsums[t] : 0;
  lds[t] = own;
  __syncthreads();
  for (int off = 1; off < 128; off <<= 1) {
    int a = (t >= off) ? lds[t - off] : 0;
    __syncthreads();
    lds[t] += a;
    __syncthreads();
  }
  if (t < nb) boffs[t] = lds[t] - own;  // exclusive
}

__global__ __launch_bounds__(256) void k_scan_add(int* __restrict__ rp,
                                                  const int* __restrict__ boffs, int n, int E) {
  int base = blockIdx.x * 1024 + threadIdx.x * 4;
  int off = boffs[blockIdx.x];
  if (base < n) {
    int4 v = *(const int4*)(rp + base);
    v.x += off; v.y += off; v.z += off; v.w += off;
    *(int4*)(rp + base) = v;
  }
  if (blockIdx.x == 0 && threadIdx.x == 0) rp[n] = E;
}

// --- bucket-base scan (one block) ------------------------------------------
__global__ __launch_bounds__(512) void k_scan_buckets(const int* __restrict__ bhist,
                                                      int* __restrict__ bases, int* __restrict__ gcursor,
                                                      int NB, int E) {
  __shared__ int lds[512];
  int t = threadIdx.x;
  int v = (t < NB) ? bhist[t] : 0;
  lds[t] = v;
  __syncthreads();
  for (int off = 1; off < 512; off <<= 1) {
    int a = (t >= off) ? lds[t - off] : 0;
    __syncthreads();
    lds[t] += a;
    __syncthreads();
  }
  int excl = lds[t] - v;
  if (t < NB) { bases[t] = excl; gcursor[t] = excl; }
  if (t == 0) bases[NB] = E;
}

// --- pass A: chunk-local histogram -> reserve runs -> dense pair append ----
__global__ __launch_bounds__(256) void k_bucket(const void* __restrict__ eidx, const int* __restrict__ flag,
                                                int* __restrict__ gcursor, int2* __restrict__ pairs, int E) {
  __shared__ int hist[BKT_MAX];
  __shared__ int basech[BKT_MAX];
  __shared__ int run[BKT_MAX];
  for (int i = threadIdx.x; i < BKT_MAX; i += 256) { hist[i] = 0; run[i] = 0; }
  __syncthreads();
  int is64 = *flag;
  int cbase = blockIdx.x * CHUNK;
  int cend = min(cbase + CHUNK, E);
  for (int e = cbase + threadIdx.x; e < cend; e += 256) {
    int d = edge_at(eidx, is64, (size_t)E + e);
    atomicAdd(&hist[d >> BKT_SHIFT], 1);
  }
  __syncthreads();
  for (int i = threadIdx.x; i < BKT_MAX; i += 256) {
    int h = hist[i];
    basech[i] = h ? atomicAdd(&gcursor[i], h) : 0;
  }
  __syncthreads();
  for (int e = cbase + threadIdx.x; e < cend; e += 256) {
    int s = edge_at(eidx, is64, (size_t)e);
    int d = edge_at(eidx, is64, (size_t)E + e);
    int b = d >> BKT_SHIFT;
    int r = atomicAdd(&run[b], 1);
    pairs[basech[b] + r] = make_int2(s, d);
  }
}

// --- pass B: one workgroup owns one bucket's CSR region --------------------
__global__ __launch_bounds__(256) void k_csr(const int* __restrict__ rp, const int* __restrict__ bases,
                                             const int2* __restrict__ pairs, int* __restrict__ csr_src,
                                             int n_nodes) {
  __shared__ int cur[256];
  int b = blockIdx.x;
  int node = (b << BKT_SHIFT) + threadIdx.x;
  cur[threadIdx.x] = (node < n_nodes) ? rp[node] : 0;
  __syncthreads();
  int lo = bases[b], hi = bases[b + 1];
  for (int i = lo + threadIdx.x; i < hi; i += 256) {
    int2 p = pairs[i];
    int q = atomicAdd(&cur[p.y & 255], 1);   // LDS cursor: single-writer region
    csr_src[q] = p.x;
  }
}

// --- GEMM1: XL = x@W1l^T, XR = x@W1r^T + b1l  (64x64 tile, LDS-staged) -----
__global__ __launch_bounds__(256) void k_gemm1(const float* __restrict__ x,
                                               const float* __restrict__ Wl, const float* __restrict__ bl,
                                               const float* __restrict__ Wr,
                                               float* __restrict__ XL, float* __restrict__ XR, int n_nodes) {
  // stride 68 floats (272B = 17*16B): float4-aligned, k-major reads land 2-way
  // on banks (free per m136).
  __shared__ float sWl[64 * 68];
  __shared__ float sWr[64 * 68];
  __shared__ float sX[64 * 68];
  int tid = threadIdx.x;
  int base = blockIdx.x * 64;

#pragma unroll
  for (int r = 0; r < 4; ++r) {              // weights: 64f x 16 float4
    int idx = tid + 256 * r;
    int f = idx >> 4, c4 = idx & 15;
    float4 wl = *(const float4*)(Wl + f * 64 + c4 * 4);
    float4 wr = *(const float4*)(Wr + f * 64 + c4 * 4);
    sWl[(c4 * 4 + 0) * 68 + f] = wl.x; sWl[(c4 * 4 + 1) * 68 + f] = wl.y;
    sWl[(c4 * 4 + 2) * 68 + f] = wl.z; sWl[(c4 * 4 + 3) * 68 + f] = wl.w;
    sWr[(c4 * 4 + 0) * 68 + f] = wr.x; sWr[(c4 * 4 + 1) * 68 + f] = wr.y;
    sWr[(c4 * 4 + 2) * 68 + f] = wr.z; sWr[(c4 * 4 + 3) * 68 + f] = wr.w;
  }
#pragma unroll
  for (int r = 0; r < 4; ++r) {              // x tile: 64n x 16 float4
    int idx = tid + 256 * r;
    int nn = idx >> 4, c4 = idx & 15;
    int node = base + nn;
    float4 xv = make_float4(0.f, 0.f, 0.f, 0.f);
    if (node < n_nodes) xv = *(const float4*)(x + (size_t)node * 64 + c4 * 4);
    sX[(c4 * 4 + 0) * 68 + nn] = xv.x; sX[(c4 * 4 + 1) * 68 + nn] = xv.y;
    sX[(c4 * 4 + 2) * 68 + nn] = xv.z; sX[(c4 * 4 + 3) * 68 + nn] = xv.w;
  }
  __syncthreads();

  int f0 = (tid & 15) * 4, n0 = (tid >> 4) * 4;
  float accL[4][4] = {{0}}, accR[4][4] = {{0}};
#pragma unroll 8
  for (int k = 0; k < 64; ++k) {
    float4 xv = *(const float4*)&sX[k * 68 + n0];
    float4 wl = *(const float4*)&sWl[k * 68 + f0];
    float4 wr = *(const float4*)&sWr[k * 68 + f0];
    float xn[4] = {xv.x, xv.y, xv.z, xv.w};
    float wlf[4] = {wl.x, wl.y, wl.z, wl.w};
    float wrf[4] = {wr.x, wr.y, wr.z, wr.w};
#pragma unroll
    for (int a = 0; a < 4; ++a)
#pragma unroll
      for (int b = 0; b < 4; ++b) {
        accL[a][b] += xn[a] * wlf[b];
        accR[a][b] += xn[a] * wrf[b];
      }
  }

  float4 blv = *(const float4*)(bl + f0);
#pragma unroll
  for (int a = 0; a < 4; ++a) {
    int node = base + n0 + a;
    if (node >= n_nodes) continue;
    float4 ol = make_float4(accL[a][0], accL[a][1], accL[a][2], accL[a][3]);
    float4 orr = make_float4(accR[a][0] + blv.x, accR[a][1] + blv.y,
                             accR[a][2] + blv.z, accR[a][3] + blv.w);
    *(float4*)(XL + (size_t)node * 64 + f0) = ol;
    *(float4*)(XR + (size_t)node * 64 + f0) = orr;
  }
}

// --- AGG1 + GEMM2 fused ----------------------------------------------------
// h = relu(mean_j XL[j] + XR) computed in registers (16 lanes x float4/node),
// then HL = h@W2l^T, HR = h@W2r^T + b2l via in-group shfl_xor dot-reduce.
// h is never written to global memory. Gather unrolled 4x for MLP (L3-latency
// bound: 410MB logical reads from a 25.6MB L3-resident table).
__global__ __launch_bounds__(256) void k_agg1g2(const int* __restrict__ rp, const int* __restrict__ csr_src,
                                                const float* __restrict__ XL, const float* __restrict__ XR,
                                                const float* __restrict__ W2l, const float* __restrict__ b2l,
                                                const float* __restrict__ W2r,
                                                float* __restrict__ HL, float* __restrict__ HR,
                                                int n_nodes) {
  int wave = threadIdx.x >> 6, lane = threadIdx.x & 63;
  int g = lane >> 4, c = lane & 15;
  int n = (blockIdx.x * 4 + wave) * 4 + g;
  if (n >= n_nodes) return;

  // per-lane slices of the 2x64 projection weights (L1-broadcast, 16B each)
  float4 wl0 = *(const float4*)(W2l + c * 4);
  float4 wl1 = *(const float4*)(W2l + 64 + c * 4);
  float4 wr0 = *(const float4*)(W2r + c * 4);
  float4 wr1 = *(const float4*)(W2r + 64 + c * 4);
  // hoisted self-row read: overlaps the gather below
  float4 xr = *(const float4*)(XR + (size_t)n * 64 + c * 4);

  int start = rp[n], end = rp[n + 1];
  float4 a0 = make_float4(0.f, 0.f, 0.f, 0.f);
  float4 a1 = make_float4(0.f, 0.f, 0.f, 0.f);
  float4 a2 = make_float4(0.f, 0.f, 0.f, 0.f);
  float4 a3 = make_float4(0.f, 0.f, 0.f, 0.f);
  int e = start;
  for (; e + 3 < end; e += 4) {               // unroll-4: 4 outstanding 256B reads
    int s0 = csr_src[e], s1 = csr_src[e + 1], s2 = csr_src[e + 2], s3 = csr_src[e + 3];
    float4 v0 = *(const float4*)(XL + (size_t)s0 * 64 + c * 4);
    float4 v1 = *(const float4*)(XL + (size_t)s1 * 64 + c * 4);
    float4 v2 = *(const float4*)(XL + (size_t)s2 * 64 + c * 4);
    float4 v3 = *(const float4*)(XL + (size_t)s3 * 64 + c * 4);
    a0.x += v0.x; a0.y += v0.y; a0.z += v0.z; a0.w += v0.w;
    a1.x += v1.x; a1.y += v1.y; a1.z += v1.z; a1.w += v1.w;
    a2.x += v2.x; a2.y += v2.y; a2.z += v2.z; a2.w += v2.w;
    a3.x += v3.x; a3.y += v3.y; a3.z += v3.z; a3.w += v3.w;
  }
  if (e + 1 < end) {
    int s0 = csr_src[e], s1 = csr_src[e + 1];
    float4 v0 = *(const float4*)(XL + (size_t)s0 * 64 + c * 4);
    float4 v1 = *(const float4*)(XL + (size_t)s1 * 64 + c * 4);
    a0.x += v0.x; a0.y += v0.y; a0.z += v0.z; a0.w += v0.w;
    a1.x += v1.x; a1.y += v1.y; a1.z += v1.z; a1.w += v1.w;
    e += 2;
  }
  if (e < end) {
    int s0 = csr_src[e];
    float4 v0 = *(const float4*)(XL + (size_t)s0 * 64 + c * 4);
    a0.x += v0.x; a0.y += v0.y; a0.z += v0.z; a0.w += v0.w;
  }
  float inv = 1.0f / fmaxf((float)(end - start), 1.0f);
  float4 h;
  h.x = fmaxf((a0.x + a1.x + a2.x + a3.x) * inv + xr.x, 0.f);
  h.y = fmaxf((a0.y + a1.y + a2.y + a3.y) * inv + xr.y, 0.f);
  h.z = fmaxf((a0.z + a1.z + a2.z + a3.z) * inv + xr.z, 0.f);
  h.w = fmaxf((a0.w + a1.w + a2.w + a3.w) * inv + xr.w, 0.f);

  // fused 64->2 projections: per-lane dot, butterfly-reduce over 16 lanes
  float p0 = h.x * wl0.x + h.y * wl0.y + h.z * wl0.z + h.w * wl0.w;
  float p1 = h.x * wl1.x + h.y * wl1.y + h.z * wl1.z + h.w * wl1.w;
  float q0 = h.x * wr0.x + h.y * wr0.y + h.z * wr0.z + h.w * wr0.w;
  float q1 = h.x * wr1.x + h.y * wr1.y + h.z * wr1.z + h.w * wr1.w;
#pragma unroll
  for (int off = 1; off < 16; off <<= 1) {
    p0 += __shfl_xor(p0, off, 16);
    p1 += __shfl_xor(p1, off, 16);
    q0 += __shfl_xor(q0, off, 16);
    q1 += __shfl_xor(q1, off, 16);
  }
  if (c == 0) {
    *(float2*)(HL + (size_t)n * 2) = make_float2(p0, p1);
    *(float2*)(HR + (size_t)n * 2) = make_float2(q0 + b2l[0], q1 + b2l[1]);
  }
}

// --- AGG2: out = mean_j HL[j] + HR  (thread per node, 2-dim features) ------
__global__ __launch_bounds__(256) void k_agg2(const int* __restrict__ rp, const int* __restrict__ csr_src,
                                              const float* __restrict__ HL, const float* __restrict__ HR,
                                              float* __restrict__ out, int n_nodes) {
  int n = blockIdx.x * 256 + threadIdx.x;
  if (n >= n_nodes) return;
  int start = rp[n], end = rp[n + 1];
  float s0 = 0.f, s1 = 0.f;
  int e = start;
  for (; e + 1 < end; e += 2) {
    int sa = csr_src[e], sb = csr_src[e + 1];
    float2 va = *(const float2*)(HL + (size_t)sa * 2);
    float2 vb = *(const float2*)(HL + (size_t)sb * 2);
    s0 += va.x + vb.x; s1 += va.y + vb.y;
  }
  if (e < end) {
    int sa = csr_src[e];
    float2 va = *(const float2*)(HL + (size_t)sa * 2);
    s0 += va.x; s1 += va.y;
  }
  float inv = 1.0f / fmaxf((float)(end - start), 1.0f);
  float2 hr = *(const float2*)(HR + (size_t)n * 2);
  out[n * 2 + 0] = s0 * inv + hr.x;
  out[n * 2 + 1] = s1 * inv + hr.y;
}

// ---------------------------------------------------------------------------
extern "C" void kernel_launch(void* const* d_in, const int* in_sizes, int n_in,
                              void* d_out, int out_size, void* d_ws, size_t ws_size,
                              hipStream_t stream) {
  const float* x   = (const float*)d_in[0];
  const void*  eix = d_in[1];
  const float* W1l = (const float*)d_in[2];
  const float* b1l = (const float*)d_in[3];
  const float* W1r = (const float*)d_in[4];
  const float* W2l = (const float*)d_in[5];
  const float* b2l = (const float*)d_in[6];
  const float* W2r = (const float*)d_in[7];
  float* out = (float*)d_out;

  const int N = in_sizes[0] / 64;       // 100000
  const int E = in_sizes[1] / 2;        // 1600000
  const int NB = (N + 255) >> BKT_SHIFT; // 391 buckets

  // workspace layout (256B-aligned chunks)
  char* base = (char*)d_ws;
  size_t off = 0;
  auto alloc = [&](size_t bytes) {
    char* p = base + off;
    off = (off + bytes + 255) & ~(size_t)255;
    return p;
  };
  int*   deg     = (int*)alloc((size_t)(N + BKT_MAX) * 4);  // deg + bhist, zeroed together
  int*   bhist   = deg + N;
  int*   rp      = (int*)alloc((size_t)(N + 1) * 4);
  int*   bases   = (int*)alloc((size_t)(BKT_MAX + 1) * 4);
  int*   gcursor = (int*)alloc((size_t)BKT_MAX * 4);
  int*   bsums   = (int*)alloc(1024);
  int*   boffs   = (int*)alloc(1024);
  int*   flag    = (int*)alloc(256);
  int*   csr_src = (int*)alloc((size_t)E * 4);
  float* XL      = (float*)alloc((size_t)N * 64 * 4);
  float* XR      = (float*)alloc((size_t)N * 64 * 4);
  float* HL      = (float*)alloc((size_t)N * 2 * 4);
  float* HR      = (float*)alloc((size_t)N * 2 * 4);
  int2*  pairs   = (int2*)XL;   // alias: pairs dead before gemm1 writes XL
  (void)ws_size;

  const int nb_scan = (N + 1023) / 1024;          // 98
  const int nb_hist = (E + 4095) / 4096;          // 391
  const int nb_bkt  = (E + CHUNK - 1) / CHUNK;    // 98

  hipMemsetAsync(deg, 0, (size_t)(N + BKT_MAX) * 4, stream);
  k_detect<<<1, 256, 0, stream>>>((const int*)eix, flag);
  k_hist<<<nb_hist, 256, 0, stream>>>(eix, flag, deg, bhist, E);
  k_scan_block<<<nb_scan, 256, 0, stream>>>(deg, rp, bsums, N);
  k_scan_sums<<<1, 128, 0, stream>>>(bsums, boffs, nb_scan);
  k_scan_add<<<nb_scan, 256, 0, stream>>>(rp, boffs, N, E);
  k_scan_buckets<<<1, 512, 0, stream>>>(bhist, bases, gcursor, NB, E);
  k_bucket<<<nb_bkt, 256, 0, stream>>>(eix, flag, gcursor, pairs, E);
  k_csr<<<NB, 256, 0, stream>>>(rp, bases, pairs, csr_src, N);

  k_gemm1<<<(N + 63) / 64, 256, 0, stream>>>(x, W1l, b1l, W1r, XL, XR, N);
  k_agg1g2<<<(N + 15) / 16, 256, 0, stream>>>(rp, csr_src, XL, XR, W2l, b2l, W2r, HL, HR, N);
  k_agg2<<<(N + 255) / 256, 256, 0, stream>>>(rp, csr_src, HL, HR, out, N);
}

// Round 7
// 247.754 us; speedup vs baseline: 1.5510x; 1.3044x over previous
//
#include <hip/hip_runtime.h>
#include <cstdint>

typedef long long i64;
typedef unsigned int u32;

// ---------------------------------------------------------------------------
// FraudGNN: 2-layer GraphSAGE (mean aggr), N=100K, E=1.6M, d 64->64->2, fp32.
// Rewrite: lin(mean(x)) == mean(lin(x))  -> transform first, aggregate after.
//   XL = x@W1l^T ; XR = x@W1r^T + b1l
//   h  = relu(meanagg(XL) + XR)            (registers only, never stored)
//   HL = h@W2l^T ; HR = h@W2r^T + b2l      (fused into the aggregation kernel)
//   out = meanagg(HL) + HR                 (2-dim gather, L2-resident)
//
// CSR build: fixed-capacity bucketed counting sort with ZERO per-edge global
// atomics. Round-3: global scatter = 138us (105MB rand writes). Round-4:
// global per-node atomic histogram = 71us (50MB atomic RMW traffic). Now:
// buckets of 256 nodes with fixed capacity CAP=5120 (mean fill 4096, +16
// sigma, overflow impossible for Binomial(1.6M, 256/1e5)); pass A reserves
// dense per-chunk runs via ~38K bucket-level atomics; pass B derives row
// start/end (the old rp scan chain) from an in-LDS 256-wide scan and does a
// single-writer scatter into the bucket's private csr region.
// ---------------------------------------------------------------------------

#define BKT_SHIFT 8          // 256 nodes per bucket
#define BKT_MAX   512        // LDS array size (NB=391 for N=100000)
#define BKT_CAP   5120       // slots per bucket in pairs/csr buffers
#define CHUNK     16384      // edges per pass-A workgroup

// --- edge dtype probe: harness doc says int32, reference says int64. Detect.
__global__ __launch_bounds__(256) void k_detect(const int* __restrict__ e, int* __restrict__ flag) {
  __shared__ int nz;
  if (threadIdx.x == 0) nz = 0;
  __syncthreads();
  // If data is int64 (values < 2^31, nonneg), every odd 32-bit word is 0.
  if (e[2 * threadIdx.x + 1] != 0) nz = 1;   // benign race, all write 1
  __syncthreads();
  if (threadIdx.x == 0) *flag = (nz == 0) ? 1 : 0;  // 1 => int64 layout
}

__device__ __forceinline__ int edge_at(const void* eidx, int is64, size_t i) {
  return is64 ? (int)((const i64*)eidx)[i] : ((const int*)eidx)[i];
}

// --- pass A: chunk-local histogram -> reserve runs -> dense packed append --
// pairs[i] = (src << 8) | (dst & 255)   (valid: N < 2^24)
__global__ __launch_bounds__(256) void k_bucket(const void* __restrict__ eidx, const int* __restrict__ flag,
                                                int* __restrict__ gcount, u32* __restrict__ pairs, int E) {
  __shared__ int hist[BKT_MAX];
  __shared__ int basech[BKT_MAX];
  __shared__ int run[BKT_MAX];
  for (int i = threadIdx.x; i < BKT_MAX; i += 256) { hist[i] = 0; run[i] = 0; }
  __syncthreads();
  int is64 = *flag;
  int cbase = blockIdx.x * CHUNK;
  int cend = min(cbase + CHUNK, E);
  for (int e = cbase + threadIdx.x; e < cend; e += 256) {
    int d = edge_at(eidx, is64, (size_t)E + e);
    atomicAdd(&hist[d >> BKT_SHIFT], 1);
  }
  __syncthreads();
  for (int i = threadIdx.x; i < BKT_MAX; i += 256) {
    int h = hist[i];
    basech[i] = h ? (i * BKT_CAP + atomicAdd(&gcount[i], h)) : 0;
  }
  __syncthreads();
  for (int e = cbase + threadIdx.x; e < cend; e += 256) {
    int s = edge_at(eidx, is64, (size_t)e);
    int d = edge_at(eidx, is64, (size_t)E + e);
    int b = d >> BKT_SHIFT;
    int r = atomicAdd(&run[b], 1);
    pairs[basech[b] + r] = ((u32)s << 8) | (u32)(d & 255);
  }
}

// --- pass B: one workgroup owns one bucket ---------------------------------
// count -> LDS scan (recovers row_ptr for free) -> single-writer scatter.
__global__ __launch_bounds__(256) void k_csr(const int* __restrict__ gcount, const u32* __restrict__ pairs,
                                             int* __restrict__ csr_src, int* __restrict__ rs,
                                             int* __restrict__ re, int n_nodes) {
  __shared__ int cnt[256];
  __shared__ int sc[256];
  __shared__ int cur[256];
  int b = blockIdx.x, t = threadIdx.x;
  cnt[t] = 0;
  __syncthreads();
  int lo = b * BKT_CAP, hi = lo + gcount[b];
  for (int i = lo + t; i < hi; i += 256)
    atomicAdd(&cnt[pairs[i] & 255], 1);
  __syncthreads();
  int v = cnt[t];
  sc[t] = v;
  __syncthreads();
  for (int off = 1; off < 256; off <<= 1) {
    int a = (t >= off) ? sc[t - off] : 0;
    __syncthreads();
    sc[t] += a;
    __syncthreads();
  }
  int start = lo + sc[t] - v;           // bucket-private exclusive scan
  int node = (b << BKT_SHIFT) + t;
  if (node < n_nodes) { rs[node] = start; re[node] = start + v; }
  cur[t] = start;
  __syncthreads();
  for (int i = lo + t; i < hi; i += 256) {
    u32 p = pairs[i];
    int q = atomicAdd(&cur[p & 255], 1);   // LDS cursor: single-writer region
    csr_src[q] = (int)(p >> 8);
  }
}

// --- GEMM1: XL = x@W1l^T, XR = x@W1r^T + b1l  (64x64 tile, LDS-staged) -----
__global__ __launch_bounds__(256) void k_gemm1(const float* __restrict__ x,
                                               const float* __restrict__ Wl, const float* __restrict__ bl,
                                               const float* __restrict__ Wr,
                                               float* __restrict__ XL, float* __restrict__ XR, int n_nodes) {
  // stride 68 floats (272B = 17*16B): float4-aligned, k-major reads land 2-way
  // on banks (free per m136).
  __shared__ float sWl[64 * 68];
  __shared__ float sWr[64 * 68];
  __shared__ float sX[64 * 68];
  int tid = threadIdx.x;
  int base = blockIdx.x * 64;

#pragma unroll
  for (int r = 0; r < 4; ++r) {              // weights: 64f x 16 float4
    int idx = tid + 256 * r;
    int f = idx >> 4, c4 = idx & 15;
    float4 wl = *(const float4*)(Wl + f * 64 + c4 * 4);
    float4 wr = *(const float4*)(Wr + f * 64 + c4 * 4);
    sWl[(c4 * 4 + 0) * 68 + f] = wl.x; sWl[(c4 * 4 + 1) * 68 + f] = wl.y;
    sWl[(c4 * 4 + 2) * 68 + f] = wl.z; sWl[(c4 * 4 + 3) * 68 + f] = wl.w;
    sWr[(c4 * 4 + 0) * 68 + f] = wr.x; sWr[(c4 * 4 + 1) * 68 + f] = wr.y;
    sWr[(c4 * 4 + 2) * 68 + f] = wr.z; sWr[(c4 * 4 + 3) * 68 + f] = wr.w;
  }
#pragma unroll
  for (int r = 0; r < 4; ++r) {              // x tile: 64n x 16 float4
    int idx = tid + 256 * r;
    int nn = idx >> 4, c4 = idx & 15;
    int node = base + nn;
    float4 xv = make_float4(0.f, 0.f, 0.f, 0.f);
    if (node < n_nodes) xv = *(const float4*)(x + (size_t)node * 64 + c4 * 4);
    sX[(c4 * 4 + 0) * 68 + nn] = xv.x; sX[(c4 * 4 + 1) * 68 + nn] = xv.y;
    sX[(c4 * 4 + 2) * 68 + nn] = xv.z; sX[(c4 * 4 + 3) * 68 + nn] = xv.w;
  }
  __syncthreads();

  int f0 = (tid & 15) * 4, n0 = (tid >> 4) * 4;
  float accL[4][4] = {{0}}, accR[4][4] = {{0}};
#pragma unroll 8
  for (int k = 0; k < 64; ++k) {
    float4 xv = *(const float4*)&sX[k * 68 + n0];
    float4 wl = *(const float4*)&sWl[k * 68 + f0];
    float4 wr = *(const float4*)&sWr[k * 68 + f0];
    float xn[4] = {xv.x, xv.y, xv.z, xv.w};
    float wlf[4] = {wl.x, wl.y, wl.z, wl.w};
    float wrf[4] = {wr.x, wr.y, wr.z, wr.w};
#pragma unroll
    for (int a = 0; a < 4; ++a)
#pragma unroll
      for (int b = 0; b < 4; ++b) {
        accL[a][b] += xn[a] * wlf[b];
        accR[a][b] += xn[a] * wrf[b];
      }
  }

  float4 blv = *(const float4*)(bl + f0);
#pragma unroll
  for (int a = 0; a < 4; ++a) {
    int node = base + n0 + a;
    if (node >= n_nodes) continue;
    float4 ol = make_float4(accL[a][0], accL[a][1], accL[a][2], accL[a][3]);
    float4 orr = make_float4(accR[a][0] + blv.x, accR[a][1] + blv.y,
                             accR[a][2] + blv.z, accR[a][3] + blv.w);
    *(float4*)(XL + (size_t)node * 64 + f0) = ol;
    *(float4*)(XR + (size_t)node * 64 + f0) = orr;
  }
}

// --- AGG1 + GEMM2 fused ----------------------------------------------------
// h = relu(mean_j XL[j] + XR) computed in registers (16 lanes x float4/node),
// then HL = h@W2l^T, HR = h@W2r^T + b2l via in-group shfl_xor dot-reduce.
// h is never written to global memory. Gather unrolled 4x for MLP (L3-latency
// bound: 410MB logical reads from a 25.6MB L3-resident table).
__global__ __launch_bounds__(256) void k_agg1g2(const int* __restrict__ rs, const int* __restrict__ re,
                                                const int* __restrict__ csr_src,
                                                const float* __restrict__ XL, const float* __restrict__ XR,
                                                const float* __restrict__ W2l, const float* __restrict__ b2l,
                                                const float* __restrict__ W2r,
                                                float* __restrict__ HL, float* __restrict__ HR,
                                                int n_nodes) {
  int wave = threadIdx.x >> 6, lane = threadIdx.x & 63;
  int g = lane >> 4, c = lane & 15;
  int n = (blockIdx.x * 4 + wave) * 4 + g;
  if (n >= n_nodes) return;

  // per-lane slices of the 2x64 projection weights (L1-broadcast, 16B each)
  float4 wl0 = *(const float4*)(W2l + c * 4);
  float4 wl1 = *(const float4*)(W2l + 64 + c * 4);
  float4 wr0 = *(const float4*)(W2r + c * 4);
  float4 wr1 = *(const float4*)(W2r + 64 + c * 4);
  // hoisted self-row read: overlaps the gather below
  float4 xr = *(const float4*)(XR + (size_t)n * 64 + c * 4);

  int start = rs[n], end = re[n];
  float4 a0 = make_float4(0.f, 0.f, 0.f, 0.f);
  float4 a1 = make_float4(0.f, 0.f, 0.f, 0.f);
  float4 a2 = make_float4(0.f, 0.f, 0.f, 0.f);
  float4 a3 = make_float4(0.f, 0.f, 0.f, 0.f);
  int e = start;
  for (; e + 3 < end; e += 4) {               // unroll-4: 4 outstanding 256B reads
    int s0 = csr_src[e], s1 = csr_src[e + 1], s2 = csr_src[e + 2], s3 = csr_src[e + 3];
    float4 v0 = *(const float4*)(XL + (size_t)s0 * 64 + c * 4);
    float4 v1 = *(const float4*)(XL + (size_t)s1 * 64 + c * 4);
    float4 v2 = *(const float4*)(XL + (size_t)s2 * 64 + c * 4);
    float4 v3 = *(const float4*)(XL + (size_t)s3 * 64 + c * 4);
    a0.x += v0.x; a0.y += v0.y; a0.z += v0.z; a0.w += v0.w;
    a1.x += v1.x; a1.y += v1.y; a1.z += v1.z; a1.w += v1.w;
    a2.x += v2.x; a2.y += v2.y; a2.z += v2.z; a2.w += v2.w;
    a3.x += v3.x; a3.y += v3.y; a3.z += v3.z; a3.w += v3.w;
  }
  if (e + 1 < end) {
    int s0 = csr_src[e], s1 = csr_src[e + 1];
    float4 v0 = *(const float4*)(XL + (size_t)s0 * 64 + c * 4);
    float4 v1 = *(const float4*)(XL + (size_t)s1 * 64 + c * 4);
    a0.x += v0.x; a0.y += v0.y; a0.z += v0.z; a0.w += v0.w;
    a1.x += v1.x; a1.y += v1.y; a1.z += v1.z; a1.w += v1.w;
    e += 2;
  }
  if (e < end) {
    int s0 = csr_src[e];
    float4 v0 = *(const float4*)(XL + (size_t)s0 * 64 + c * 4);
    a0.x += v0.x; a0.y += v0.y; a0.z += v0.z; a0.w += v0.w;
  }
  float inv = 1.0f / fmaxf((float)(end - start), 1.0f);
  float4 h;
  h.x = fmaxf((a0.x + a1.x + a2.x + a3.x) * inv + xr.x, 0.f);
  h.y = fmaxf((a0.y + a1.y + a2.y + a3.y) * inv + xr.y, 0.f);
  h.z = fmaxf((a0.z + a1.z + a2.z + a3.z) * inv + xr.z, 0.f);
  h.w = fmaxf((a0.w + a1.w + a2.w + a3.w) * inv + xr.w, 0.f);

  // fused 64->2 projections: per-lane dot, butterfly-reduce over 16 lanes
  float p0 = h.x * wl0.x + h.y * wl0.y + h.z * wl0.z + h.w * wl0.w;
  float p1 = h.x * wl1.x + h.y * wl1.y + h.z * wl1.z + h.w * wl1.w;
  float q0 = h.x * wr0.x + h.y * wr0.y + h.z * wr0.z + h.w * wr0.w;
  float q1 = h.x * wr1.x + h.y * wr1.y + h.z * wr1.z + h.w * wr1.w;
#pragma unroll
  for (int off = 1; off < 16; off <<= 1) {
    p0 += __shfl_xor(p0, off, 16);
    p1 += __shfl_xor(p1, off, 16);
    q0 += __shfl_xor(q0, off, 16);
    q1 += __shfl_xor(q1, off, 16);
  }
  if (c == 0) {
    *(float2*)(HL + (size_t)n * 2) = make_float2(p0, p1);
    *(float2*)(HR + (size_t)n * 2) = make_float2(q0 + b2l[0], q1 + b2l[1]);
  }
}

// --- AGG2: out = mean_j HL[j] + HR  (thread per node, 2-dim features) ------
__global__ __launch_bounds__(256) void k_agg2(const int* __restrict__ rs, const int* __restrict__ re,
                                              const int* __restrict__ csr_src,
                                              const float* __restrict__ HL, const float* __restrict__ HR,
                                              float* __restrict__ out, int n_nodes) {
  int n = blockIdx.x * 256 + threadIdx.x;
  if (n >= n_nodes) return;
  int start = rs[n], end = re[n];
  float s0 = 0.f, s1 = 0.f;
  int e = start;
  for (; e + 1 < end; e += 2) {
    int sa = csr_src[e], sb = csr_src[e + 1];
    float2 va = *(const float2*)(HL + (size_t)sa * 2);
    float2 vb = *(const float2*)(HL + (size_t)sb * 2);
    s0 += va.x + vb.x; s1 += va.y + vb.y;
  }
  if (e < end) {
    int sa = csr_src[e];
    float2 va = *(const float2*)(HL + (size_t)sa * 2);
    s0 += va.x; s1 += va.y;
  }
  float inv = 1.0f / fmaxf((float)(end - start), 1.0f);
  float2 hr = *(const float2*)(HR + (size_t)n * 2);
  out[n * 2 + 0] = s0 * inv + hr.x;
  out[n * 2 + 1] = s1 * inv + hr.y;
}

// ---------------------------------------------------------------------------
extern "C" void kernel_launch(void* const* d_in, const int* in_sizes, int n_in,
                              void* d_out, int out_size, void* d_ws, size_t ws_size,
                              hipStream_t stream) {
  const float* x   = (const float*)d_in[0];
  const void*  eix = d_in[1];
  const float* W1l = (const float*)d_in[2];
  const float* b1l = (const float*)d_in[3];
  const float* W1r = (const float*)d_in[4];
  const float* W2l = (const float*)d_in[5];
  const float* b2l = (const float*)d_in[6];
  const float* W2r = (const float*)d_in[7];
  float* out = (float*)d_out;

  const int N = in_sizes[0] / 64;        // 100000
  const int E = in_sizes[1] / 2;         // 1600000
  const int NB = (N + 255) >> BKT_SHIFT; // 391 buckets

  // workspace layout (256B-aligned chunks)
  char* base = (char*)d_ws;
  size_t off = 0;
  auto alloc = [&](size_t bytes) {
    char* p = base + off;
    off = (off + bytes + 255) & ~(size_t)255;
    return p;
  };
  int*   gcount  = (int*)alloc((size_t)BKT_MAX * 4);
  int*   flag    = (int*)alloc(256);
  int*   rs      = (int*)alloc((size_t)N * 4);
  int*   re      = (int*)alloc((size_t)N * 4);
  int*   csr_src = (int*)alloc((size_t)NB * BKT_CAP * 4);   // 8.0 MB (bucketed)
  float* XL      = (float*)alloc((size_t)N * 64 * 4);
  float* XR      = (float*)alloc((size_t)N * 64 * 4);
  float* HL      = (float*)alloc((size_t)N * 2 * 4);
  float* HR      = (float*)alloc((size_t)N * 2 * 4);
  u32*   pairs   = (u32*)XL;   // alias: pairs (8.0MB) dead before gemm1 writes XL
  (void)ws_size;

  const int nb_bkt = (E + CHUNK - 1) / CHUNK;    // 98

  hipMemsetAsync(gcount, 0, (size_t)BKT_MAX * 4, stream);
  k_detect<<<1, 256, 0, stream>>>((const int*)eix, flag);
  k_bucket<<<nb_bkt, 256, 0, stream>>>(eix, flag, gcount, pairs, E);
  k_csr<<<NB, 256, 0, stream>>>(gcount, pairs, csr_src, rs, re, N);

  k_gemm1<<<(N + 63) / 64, 256, 0, stream>>>(x, W1l, b1l, W1r, XL, XR, N);
  k_agg1g2<<<(N + 15) / 16, 256, 0, stream>>>(rs, re, csr_src, XL, XR, W2l, b2l, W2r, HL, HR, N);
  k_agg2<<<(N + 255) / 256, 256, 0, stream>>>(rs, re, csr_src, HL, HR, out, N);
}

// Round 8
// 232.302 us; speedup vs baseline: 1.6541x; 1.0665x over previous
//
#include <hip/hip_runtime.h>
#include <cstdint>

typedef long long i64;
typedef unsigned int u32;

// ---------------------------------------------------------------------------
// FraudGNN: 2-layer GraphSAGE (mean aggr), N=100K, E=1.6M, d 64->64->2, fp32.
// Rewrite: lin(mean(x)) == mean(lin(x))  -> transform first, aggregate after.
//   XL = x@W1l^T ; XR = x@W1r^T + b1l
//   h  = relu(meanagg(XL) + XR)            (registers only, never stored)
//   HL = h@W2l^T ; HR = h@W2r^T + b2l      (fused into the aggregation kernel)
//   out = meanagg(HL) + HR                 (2-dim gather, L2-resident)
//
// CSR build: fixed-capacity bucketed counting sort with ZERO per-edge global
// atomics. Round-3: global scatter = 138us (105MB rand writes). Round-4:
// global per-node atomic histogram = 71us (50MB atomic RMW traffic).
// Round-7: CHUNK=16384 gave only 98 workgroups -> OccupancyPercent 3.8%,
// latency-bound at 203GB/s -> 60-69us. Now CHUNK=2048 (782 WGs, ~3 blocks/CU,
// 8x TLP): per-chunk runs shrink to ~5 edges (write amp ~20MB, ~3us floor) and
// bucket reservations rise to ~300K (L2 pipelines same-line atomics, ~5us),
// both cheap against the 8x latency-hiding win.
// ---------------------------------------------------------------------------

#define BKT_SHIFT 8          // 256 nodes per bucket
#define BKT_MAX   512        // LDS array size (NB=391 for N=100000)
#define BKT_CAP   5120       // slots per bucket in pairs/csr buffers
#define CHUNK     2048       // edges per pass-A workgroup (782 WGs)

// --- edge dtype probe: harness doc says int32, reference says int64. Detect.
__global__ __launch_bounds__(256) void k_detect(const int* __restrict__ e, int* __restrict__ flag) {
  __shared__ int nz;
  if (threadIdx.x == 0) nz = 0;
  __syncthreads();
  // If data is int64 (values < 2^31, nonneg), every odd 32-bit word is 0.
  if (e[2 * threadIdx.x + 1] != 0) nz = 1;   // benign race, all write 1
  __syncthreads();
  if (threadIdx.x == 0) *flag = (nz == 0) ? 1 : 0;  // 1 => int64 layout
}

__device__ __forceinline__ int edge_at(const void* eidx, int is64, size_t i) {
  return is64 ? (int)((const i64*)eidx)[i] : ((const int*)eidx)[i];
}

// --- pass A: chunk-local histogram -> reserve runs -> dense packed append --
// pairs[i] = (src << 8) | (dst & 255)   (valid: N < 2^24)
__global__ __launch_bounds__(256) void k_bucket(const void* __restrict__ eidx, const int* __restrict__ flag,
                                                int* __restrict__ gcount, u32* __restrict__ pairs, int E) {
  __shared__ int hist[BKT_MAX];
  __shared__ int basech[BKT_MAX];
  __shared__ int run[BKT_MAX];
  for (int i = threadIdx.x; i < BKT_MAX; i += 256) { hist[i] = 0; run[i] = 0; }
  __syncthreads();
  int is64 = *flag;
  int cbase = blockIdx.x * CHUNK;
  int cend = min(cbase + CHUNK, E);
  for (int e = cbase + threadIdx.x; e < cend; e += 256) {
    int d = edge_at(eidx, is64, (size_t)E + e);
    atomicAdd(&hist[d >> BKT_SHIFT], 1);
  }
  __syncthreads();
  for (int i = threadIdx.x; i < BKT_MAX; i += 256) {
    int h = hist[i];
    basech[i] = h ? (i * BKT_CAP + atomicAdd(&gcount[i], h)) : 0;
  }
  __syncthreads();
  for (int e = cbase + threadIdx.x; e < cend; e += 256) {
    int s = edge_at(eidx, is64, (size_t)e);
    int d = edge_at(eidx, is64, (size_t)E + e);
    int b = d >> BKT_SHIFT;
    int r = atomicAdd(&run[b], 1);
    pairs[basech[b] + r] = ((u32)s << 8) | (u32)(d & 255);
  }
}

// --- pass B: one workgroup owns one bucket ---------------------------------
// count -> LDS scan (recovers row_ptr for free) -> single-writer scatter.
__global__ __launch_bounds__(256) void k_csr(const int* __restrict__ gcount, const u32* __restrict__ pairs,
                                             int* __restrict__ csr_src, int* __restrict__ rs,
                                             int* __restrict__ re, int n_nodes) {
  __shared__ int cnt[256];
  __shared__ int sc[256];
  __shared__ int cur[256];
  int b = blockIdx.x, t = threadIdx.x;
  cnt[t] = 0;
  __syncthreads();
  int lo = b * BKT_CAP, hi = lo + gcount[b];
  for (int i = lo + t; i < hi; i += 256)
    atomicAdd(&cnt[pairs[i] & 255], 1);
  __syncthreads();
  int v = cnt[t];
  sc[t] = v;
  __syncthreads();
  for (int off = 1; off < 256; off <<= 1) {
    int a = (t >= off) ? sc[t - off] : 0;
    __syncthreads();
    sc[t] += a;
    __syncthreads();
  }
  int start = lo + sc[t] - v;           // bucket-private exclusive scan
  int node = (b << BKT_SHIFT) + t;
  if (node < n_nodes) { rs[node] = start; re[node] = start + v; }
  cur[t] = start;
  __syncthreads();
  for (int i = lo + t; i < hi; i += 256) {
    u32 p = pairs[i];
    int q = atomicAdd(&cur[p & 255], 1);   // LDS cursor: single-writer region
    csr_src[q] = (int)(p >> 8);
  }
}

// --- GEMM1: XL = x@W1l^T, XR = x@W1r^T + b1l  (64x64 tile, LDS-staged) -----
__global__ __launch_bounds__(256) void k_gemm1(const float* __restrict__ x,
                                               const float* __restrict__ Wl, const float* __restrict__ bl,
                                               const float* __restrict__ Wr,
                                               float* __restrict__ XL, float* __restrict__ XR, int n_nodes) {
  // stride 68 floats (272B = 17*16B): float4-aligned, k-major reads land 2-way
  // on banks (free per m136).
  __shared__ float sWl[64 * 68];
  __shared__ float sWr[64 * 68];
  __shared__ float sX[64 * 68];
  int tid = threadIdx.x;
  int base = blockIdx.x * 64;

#pragma unroll
  for (int r = 0; r < 4; ++r) {              // weights: 64f x 16 float4
    int idx = tid + 256 * r;
    int f = idx >> 4, c4 = idx & 15;
    float4 wl = *(const float4*)(Wl + f * 64 + c4 * 4);
    float4 wr = *(const float4*)(Wr + f * 64 + c4 * 4);
    sWl[(c4 * 4 + 0) * 68 + f] = wl.x; sWl[(c4 * 4 + 1) * 68 + f] = wl.y;
    sWl[(c4 * 4 + 2) * 68 + f] = wl.z; sWl[(c4 * 4 + 3) * 68 + f] = wl.w;
    sWr[(c4 * 4 + 0) * 68 + f] = wr.x; sWr[(c4 * 4 + 1) * 68 + f] = wr.y;
    sWr[(c4 * 4 + 2) * 68 + f] = wr.z; sWr[(c4 * 4 + 3) * 68 + f] = wr.w;
  }
#pragma unroll
  for (int r = 0; r < 4; ++r) {              // x tile: 64n x 16 float4
    int idx = tid + 256 * r;
    int nn = idx >> 4, c4 = idx & 15;
    int node = base + nn;
    float4 xv = make_float4(0.f, 0.f, 0.f, 0.f);
    if (node < n_nodes) xv = *(const float4*)(x + (size_t)node * 64 + c4 * 4);
    sX[(c4 * 4 + 0) * 68 + nn] = xv.x; sX[(c4 * 4 + 1) * 68 + nn] = xv.y;
    sX[(c4 * 4 + 2) * 68 + nn] = xv.z; sX[(c4 * 4 + 3) * 68 + nn] = xv.w;
  }
  __syncthreads();

  int f0 = (tid & 15) * 4, n0 = (tid >> 4) * 4;
  float accL[4][4] = {{0}}, accR[4][4] = {{0}};
#pragma unroll 8
  for (int k = 0; k < 64; ++k) {
    float4 xv = *(const float4*)&sX[k * 68 + n0];
    float4 wl = *(const float4*)&sWl[k * 68 + f0];
    float4 wr = *(const float4*)&sWr[k * 68 + f0];
    float xn[4] = {xv.x, xv.y, xv.z, xv.w};
    float wlf[4] = {wl.x, wl.y, wl.z, wl.w};
    float wrf[4] = {wr.x, wr.y, wr.z, wr.w};
#pragma unroll
    for (int a = 0; a < 4; ++a)
#pragma unroll
      for (int b = 0; b < 4; ++b) {
        accL[a][b] += xn[a] * wlf[b];
        accR[a][b] += xn[a] * wrf[b];
      }
  }

  float4 blv = *(const float4*)(bl + f0);
#pragma unroll
  for (int a = 0; a < 4; ++a) {
    int node = base + n0 + a;
    if (node >= n_nodes) continue;
    float4 ol = make_float4(accL[a][0], accL[a][1], accL[a][2], accL[a][3]);
    float4 orr = make_float4(accR[a][0] + blv.x, accR[a][1] + blv.y,
                             accR[a][2] + blv.z, accR[a][3] + blv.w);
    *(float4*)(XL + (size_t)node * 64 + f0) = ol;
    *(float4*)(XR + (size_t)node * 64 + f0) = orr;
  }
}

// --- AGG1 + GEMM2 fused ----------------------------------------------------
// h = relu(mean_j XL[j] + XR) computed in registers (16 lanes x float4/node),
// then HL = h@W2l^T, HR = h@W2r^T + b2l via in-group shfl_xor dot-reduce.
// h is never written to global memory. Gather unrolled 4x for MLP (L3-latency
// bound: 410MB logical reads from a 25.6MB L3-resident table).
__global__ __launch_bounds__(256) void k_agg1g2(const int* __restrict__ rs, const int* __restrict__ re,
                                                const int* __restrict__ csr_src,
                                                const float* __restrict__ XL, const float* __restrict__ XR,
                                                const float* __restrict__ W2l, const float* __restrict__ b2l,
                                                const float* __restrict__ W2r,
                                                float* __restrict__ HL, float* __restrict__ HR,
                                                int n_nodes) {
  int wave = threadIdx.x >> 6, lane = threadIdx.x & 63;
  int g = lane >> 4, c = lane & 15;
  int n = (blockIdx.x * 4 + wave) * 4 + g;
  if (n >= n_nodes) return;

  // per-lane slices of the 2x64 projection weights (L1-broadcast, 16B each)
  float4 wl0 = *(const float4*)(W2l + c * 4);
  float4 wl1 = *(const float4*)(W2l + 64 + c * 4);
  float4 wr0 = *(const float4*)(W2r + c * 4);
  float4 wr1 = *(const float4*)(W2r + 64 + c * 4);
  // hoisted self-row read: overlaps the gather below
  float4 xr = *(const float4*)(XR + (size_t)n * 64 + c * 4);

  int start = rs[n], end = re[n];
  float4 a0 = make_float4(0.f, 0.f, 0.f, 0.f);
  float4 a1 = make_float4(0.f, 0.f, 0.f, 0.f);
  float4 a2 = make_float4(0.f, 0.f, 0.f, 0.f);
  float4 a3 = make_float4(0.f, 0.f, 0.f, 0.f);
  int e = start;
  for (; e + 3 < end; e += 4) {               // unroll-4: 4 outstanding 256B reads
    int s0 = csr_src[e], s1 = csr_src[e + 1], s2 = csr_src[e + 2], s3 = csr_src[e + 3];
    float4 v0 = *(const float4*)(XL + (size_t)s0 * 64 + c * 4);
    float4 v1 = *(const float4*)(XL + (size_t)s1 * 64 + c * 4);
    float4 v2 = *(const float4*)(XL + (size_t)s2 * 64 + c * 4);
    float4 v3 = *(const float4*)(XL + (size_t)s3 * 64 + c * 4);
    a0.x += v0.x; a0.y += v0.y; a0.z += v0.z; a0.w += v0.w;
    a1.x += v1.x; a1.y += v1.y; a1.z += v1.z; a1.w += v1.w;
    a2.x += v2.x; a2.y += v2.y; a2.z += v2.z; a2.w += v2.w;
    a3.x += v3.x; a3.y += v3.y; a3.z += v3.z; a3.w += v3.w;
  }
  if (e + 1 < end) {
    int s0 = csr_src[e], s1 = csr_src[e + 1];
    float4 v0 = *(const float4*)(XL + (size_t)s0 * 64 + c * 4);
    float4 v1 = *(const float4*)(XL + (size_t)s1 * 64 + c * 4);
    a0.x += v0.x; a0.y += v0.y; a0.z += v0.z; a0.w += v0.w;
    a1.x += v1.x; a1.y += v1.y; a1.z += v1.z; a1.w += v1.w;
    e += 2;
  }
  if (e < end) {
    int s0 = csr_src[e];
    float4 v0 = *(const float4*)(XL + (size_t)s0 * 64 + c * 4);
    a0.x += v0.x; a0.y += v0.y; a0.z += v0.z; a0.w += v0.w;
  }
  float inv = 1.0f / fmaxf((float)(end - start), 1.0f);
  float4 h;
  h.x = fmaxf((a0.x + a1.x + a2.x + a3.x) * inv + xr.x, 0.f);
  h.y = fmaxf((a0.y + a1.y + a2.y + a3.y) * inv + xr.y, 0.f);
  h.z = fmaxf((a0.z + a1.z + a2.z + a3.z) * inv + xr.z, 0.f);
  h.w = fmaxf((a0.w + a1.w + a2.w + a3.w) * inv + xr.w, 0.f);

  // fused 64->2 projections: per-lane dot, butterfly-reduce over 16 lanes
  float p0 = h.x * wl0.x + h.y * wl0.y + h.z * wl0.z + h.w * wl0.w;
  float p1 = h.x * wl1.x + h.y * wl1.y + h.z * wl1.z + h.w * wl1.w;
  float q0 = h.x * wr0.x + h.y * wr0.y + h.z * wr0.z + h.w * wr0.w;
  float q1 = h.x * wr1.x + h.y * wr1.y + h.z * wr1.z + h.w * wr1.w;
#pragma unroll
  for (int off = 1; off < 16; off <<= 1) {
    p0 += __shfl_xor(p0, off, 16);
    p1 += __shfl_xor(p1, off, 16);
    q0 += __shfl_xor(q0, off, 16);
    q1 += __shfl_xor(q1, off, 16);
  }
  if (c == 0) {
    *(float2*)(HL + (size_t)n * 2) = make_float2(p0, p1);
    *(float2*)(HR + (size_t)n * 2) = make_float2(q0 + b2l[0], q1 + b2l[1]);
  }
}

// --- AGG2: out = mean_j HL[j] + HR  (thread per node, 2-dim features) ------
__global__ __launch_bounds__(256) void k_agg2(const int* __restrict__ rs, const int* __restrict__ re,
                                              const int* __restrict__ csr_src,
                                              const float* __restrict__ HL, const float* __restrict__ HR,
                                              float* __restrict__ out, int n_nodes) {
  int n = blockIdx.x * 256 + threadIdx.x;
  if (n >= n_nodes) return;
  int start = rs[n], end = re[n];
  float s0 = 0.f, s1 = 0.f;
  int e = start;
  for (; e + 1 < end; e += 2) {
    int sa = csr_src[e], sb = csr_src[e + 1];
    float2 va = *(const float2*)(HL + (size_t)sa * 2);
    float2 vb = *(const float2*)(HL + (size_t)sb * 2);
    s0 += va.x + vb.x; s1 += va.y + vb.y;
  }
  if (e < end) {
    int sa = csr_src[e];
    float2 va = *(const float2*)(HL + (size_t)sa * 2);
    s0 += va.x; s1 += va.y;
  }
  float inv = 1.0f / fmaxf((float)(end - start), 1.0f);
  float2 hr = *(const float2*)(HR + (size_t)n * 2);
  out[n * 2 + 0] = s0 * inv + hr.x;
  out[n * 2 + 1] = s1 * inv + hr.y;
}

// ---------------------------------------------------------------------------
extern "C" void kernel_launch(void* const* d_in, const int* in_sizes, int n_in,
                              void* d_out, int out_size, void* d_ws, size_t ws_size,
                              hipStream_t stream) {
  const float* x   = (const float*)d_in[0];
  const void*  eix = d_in[1];
  const float* W1l = (const float*)d_in[2];
  const float* b1l = (const float*)d_in[3];
  const float* W1r = (const float*)d_in[4];
  const float* W2l = (const float*)d_in[5];
  const float* b2l = (const float*)d_in[6];
  const float* W2r = (const float*)d_in[7];
  float* out = (float*)d_out;

  const int N = in_sizes[0] / 64;        // 100000
  const int E = in_sizes[1] / 2;         // 1600000
  const int NB = (N + 255) >> BKT_SHIFT; // 391 buckets

  // workspace layout (256B-aligned chunks)
  char* base = (char*)d_ws;
  size_t off = 0;
  auto alloc = [&](size_t bytes) {
    char* p = base + off;
    off = (off + bytes + 255) & ~(size_t)255;
    return p;
  };
  int*   gcount  = (int*)alloc((size_t)BKT_MAX * 4);
  int*   flag    = (int*)alloc(256);
  int*   rs      = (int*)alloc((size_t)N * 4);
  int*   re      = (int*)alloc((size_t)N * 4);
  int*   csr_src = (int*)alloc((size_t)NB * BKT_CAP * 4);   // 8.0 MB (bucketed)
  float* XL      = (float*)alloc((size_t)N * 64 * 4);
  float* XR      = (float*)alloc((size_t)N * 64 * 4);
  float* HL      = (float*)alloc((size_t)N * 2 * 4);
  float* HR      = (float*)alloc((size_t)N * 2 * 4);
  u32*   pairs   = (u32*)XL;   // alias: pairs (8.0MB) dead before gemm1 writes XL
  (void)ws_size;

  const int nb_bkt = (E + CHUNK - 1) / CHUNK;    // 782

  hipMemsetAsync(gcount, 0, (size_t)BKT_MAX * 4, stream);
  k_detect<<<1, 256, 0, stream>>>((const int*)eix, flag);
  k_bucket<<<nb_bkt, 256, 0, stream>>>(eix, flag, gcount, pairs, E);
  k_csr<<<NB, 256, 0, stream>>>(gcount, pairs, csr_src, rs, re, N);

  k_gemm1<<<(N + 63) / 64, 256, 0, stream>>>(x, W1l, b1l, W1r, XL, XR, N);
  k_agg1g2<<<(N + 15) / 16, 256, 0, stream>>>(rs, re, csr_src, XL, XR, W2l, b2l, W2r, HL, HR, N);
  k_agg2<<<(N + 255) / 256, 256, 0, stream>>>(rs, re, csr_src, HL, HR, out, N);
}

// Round 9
// 219.383 us; speedup vs baseline: 1.7515x; 1.0589x over previous
//
#include <hip/hip_runtime.h>
#include <cstdint>

typedef long long i64;
typedef unsigned int u32;

// ---------------------------------------------------------------------------
// FraudGNN: 2-layer GraphSAGE (mean aggr), N=100K, E=1.6M, d 64->64->2, fp32.
// Rewrite: lin(mean(x)) == mean(lin(x))  -> transform first, aggregate after.
//   XL = x@W1l^T ; XR = x@W1r^T + b1l
//   h  = relu(meanagg(XL) + XR)            (registers only, never stored)
//   HL = h@W2l^T ; HR = h@W2r^T + b2l      (fused into the aggregation kernel)
//   out = meanagg(HL) + HR                 (2-dim gather, L2-resident)
//
// CSR build: fixed-capacity bucketed counting sort, zero per-edge global
// atomics (round-3: global scatter 138us/105MB writes; round-4: global atomic
// histogram 71us/50MB RMW; round-7: CHUNK=16384 -> 3.8% occupancy, 60us).
//
// Round-9: (a) bucket pass-A and GEMM1 are independent -> fused into ONE
// kernel as heterogeneous blocks (bucket blocks first) so the VALU-bound GEMM
// overlaps the latency-bound bucket scatter; (b) bucket body register-stages
// 8 edges/thread (kills the 25.6MB second edge read); (c) k_csr: 512 thr +
// uint4 pair loads; (d) agg gather unroll 4->8 (VALUBusy was 19%, occ 60%).
// ---------------------------------------------------------------------------

#define BKT_SHIFT 8          // 256 nodes per bucket
#define BKT_MAX   512        // LDS array size (NB=391 for N=100000)
#define BKT_CAP   5120       // slots per bucket (mean 4096 +16 sigma)
#define CHUNK     2048       // edges per bucket block

__device__ __forceinline__ int edge_at(const void* eidx, int is64, size_t i) {
  return is64 ? (int)((const i64*)eidx)[i] : ((const int*)eidx)[i];
}

// --- k_pre: heterogeneous blocks: [0,nbkt) bucket pass-A | [nbkt,..) GEMM1 --
__global__ __launch_bounds__(256) void k_pre(const void* __restrict__ eidx,
                                             int* __restrict__ gcount, u32* __restrict__ pairs, int E,
                                             const float* __restrict__ x,
                                             const float* __restrict__ Wl, const float* __restrict__ bl,
                                             const float* __restrict__ Wr,
                                             float* __restrict__ XL, float* __restrict__ XR,
                                             int n_nodes, int nbkt) {
  __shared__ float smem[64 * 68 * 3];          // 52.2KB, shared by both roles
  int tid = threadIdx.x;

  if ((int)blockIdx.x < nbkt) {
    // ---------------- bucket pass-A ----------------
    int* hist   = (int*)smem;                  // [BKT_MAX]
    int* basech = hist + BKT_MAX;              // [BKT_MAX]
    int* run    = basech + BKT_MAX;            // [BKT_MAX]
    int* nzp    = run + BKT_MAX;               // [1]
    for (int i = tid; i < BKT_MAX; i += 256) { hist[i] = 0; run[i] = 0; }
    if (tid == 0) *nzp = 0;
    __syncthreads();
    // inline dtype probe: int64 layout => odd 32-bit words all zero
    if (((const int*)eidx)[2 * tid + 1] != 0) *nzp = 1;
    __syncthreads();
    int is64 = (*nzp == 0);

    int cbase = blockIdx.x * CHUNK;
    int sreg[8], dreg[8];
#pragma unroll
    for (int i = 0; i < 8; ++i) {              // stage 8 edges/thread in regs
      int e = cbase + tid + 256 * i;
      bool v = e < E;
      sreg[i] = v ? edge_at(eidx, is64, (size_t)e) : 0;
      dreg[i] = v ? edge_at(eidx, is64, (size_t)E + e) : -1;
      if (v) atomicAdd(&hist[dreg[i] >> BKT_SHIFT], 1);
    }
    __syncthreads();
    for (int i = tid; i < BKT_MAX; i += 256) {
      int h = hist[i];
      basech[i] = h ? (i * BKT_CAP + atomicAdd(&gcount[i], h)) : 0;
    }
    __syncthreads();
#pragma unroll
    for (int i = 0; i < 8; ++i) {
      if (dreg[i] >= 0) {
        int b = dreg[i] >> BKT_SHIFT;
        int r = atomicAdd(&run[b], 1);
        pairs[basech[b] + r] = ((u32)sreg[i] << 8) | (u32)(dreg[i] & 255);
      }
    }
    return;
  }

  // ---------------- GEMM1: XL = x@Wl^T, XR = x@Wr^T + bl ----------------
  // stride 68 floats: float4-aligned, 2-way bank aliasing (free per m136)
  float* sWl = smem;                           // [64*68]
  float* sWr = smem + 64 * 68;
  float* sX  = smem + 2 * 64 * 68;
  int base = (blockIdx.x - nbkt) * 64;

#pragma unroll
  for (int r = 0; r < 4; ++r) {                // weights: 64f x 16 float4
    int idx = tid + 256 * r;
    int f = idx >> 4, c4 = idx & 15;
    float4 wl = *(const float4*)(Wl + f * 64 + c4 * 4);
    float4 wr = *(const float4*)(Wr + f * 64 + c4 * 4);
    sWl[(c4 * 4 + 0) * 68 + f] = wl.x; sWl[(c4 * 4 + 1) * 68 + f] = wl.y;
    sWl[(c4 * 4 + 2) * 68 + f] = wl.z; sWl[(c4 * 4 + 3) * 68 + f] = wl.w;
    sWr[(c4 * 4 + 0) * 68 + f] = wr.x; sWr[(c4 * 4 + 1) * 68 + f] = wr.y;
    sWr[(c4 * 4 + 2) * 68 + f] = wr.z; sWr[(c4 * 4 + 3) * 68 + f] = wr.w;
  }
#pragma unroll
  for (int r = 0; r < 4; ++r) {                // x tile: 64n x 16 float4
    int idx = tid + 256 * r;
    int nn = idx >> 4, c4 = idx & 15;
    int node = base + nn;
    float4 xv = make_float4(0.f, 0.f, 0.f, 0.f);
    if (node < n_nodes) xv = *(const float4*)(x + (size_t)node * 64 + c4 * 4);
    sX[(c4 * 4 + 0) * 68 + nn] = xv.x; sX[(c4 * 4 + 1) * 68 + nn] = xv.y;
    sX[(c4 * 4 + 2) * 68 + nn] = xv.z; sX[(c4 * 4 + 3) * 68 + nn] = xv.w;
  }
  __syncthreads();

  int f0 = (tid & 15) * 4, n0 = (tid >> 4) * 4;
  float accL[4][4] = {{0}}, accR[4][4] = {{0}};
#pragma unroll 8
  for (int k = 0; k < 64; ++k) {
    float4 xv = *(const float4*)&sX[k * 68 + n0];
    float4 wl = *(const float4*)&sWl[k * 68 + f0];
    float4 wr = *(const float4*)&sWr[k * 68 + f0];
    float xn[4] = {xv.x, xv.y, xv.z, xv.w};
    float wlf[4] = {wl.x, wl.y, wl.z, wl.w};
    float wrf[4] = {wr.x, wr.y, wr.z, wr.w};
#pragma unroll
    for (int a = 0; a < 4; ++a)
#pragma unroll
      for (int b = 0; b < 4; ++b) {
        accL[a][b] += xn[a] * wlf[b];
        accR[a][b] += xn[a] * wrf[b];
      }
  }

  float4 blv = *(const float4*)(bl + f0);
#pragma unroll
  for (int a = 0; a < 4; ++a) {
    int node = base + n0 + a;
    if (node >= n_nodes) continue;
    float4 ol = make_float4(accL[a][0], accL[a][1], accL[a][2], accL[a][3]);
    float4 orr = make_float4(accR[a][0] + blv.x, accR[a][1] + blv.y,
                             accR[a][2] + blv.z, accR[a][3] + blv.w);
    *(float4*)(XL + (size_t)node * 64 + f0) = ol;
    *(float4*)(XR + (size_t)node * 64 + f0) = orr;
  }
}

// --- pass B: one workgroup (512 thr) owns one bucket -----------------------
// count -> LDS scan (recovers row_ptr for free) -> single-writer scatter.
__global__ __launch_bounds__(512) void k_csr(const int* __restrict__ gcount, const u32* __restrict__ pairs,
                                             int* __restrict__ csr_src, int* __restrict__ rs,
                                             int* __restrict__ re, int n_nodes) {
  __shared__ int cnt[256];
  __shared__ int sc[256];
  __shared__ int cur[256];
  int b = blockIdx.x, t = threadIdx.x;
  if (t < 256) cnt[t] = 0;
  __syncthreads();
  int n = gcount[b];
  int lo = b * BKT_CAP, hi = lo + n;
  int tail = n & 3;
  for (int i = lo + t * 4; i + 3 < hi; i += 2048) {     // uint4: 4 pairs/iter
    uint4 p = *(const uint4*)(pairs + i);
    atomicAdd(&cnt[p.x & 255], 1); atomicAdd(&cnt[p.y & 255], 1);
    atomicAdd(&cnt[p.z & 255], 1); atomicAdd(&cnt[p.w & 255], 1);
  }
  if (t < tail) atomicAdd(&cnt[pairs[hi - tail + t] & 255], 1);
  __syncthreads();
  int v = (t < 256) ? cnt[t] : 0;
  if (t < 256) sc[t] = v;
  __syncthreads();
  for (int off = 1; off < 256; off <<= 1) {
    int a = (t >= off && t < 256) ? sc[t - off] : 0;
    __syncthreads();
    if (t < 256) sc[t] += a;
    __syncthreads();
  }
  if (t < 256) {
    int start = lo + sc[t] - v;          // bucket-private exclusive scan
    int node = (b << BKT_SHIFT) + t;
    if (node < n_nodes) { rs[node] = start; re[node] = start + v; }
    cur[t] = start;
  }
  __syncthreads();
  for (int i = lo + t * 4; i + 3 < hi; i += 2048) {
    uint4 p = *(const uint4*)(pairs + i);
    csr_src[atomicAdd(&cur[p.x & 255], 1)] = (int)(p.x >> 8);
    csr_src[atomicAdd(&cur[p.y & 255], 1)] = (int)(p.y >> 8);
    csr_src[atomicAdd(&cur[p.z & 255], 1)] = (int)(p.z >> 8);
    csr_src[atomicAdd(&cur[p.w & 255], 1)] = (int)(p.w >> 8);
  }
  if (t < tail) {
    u32 p = pairs[hi - tail + t];
    csr_src[atomicAdd(&cur[p & 255], 1)] = (int)(p >> 8);
  }
}

// --- AGG1 + GEMM2 fused ----------------------------------------------------
// h = relu(mean_j XL[j] + XR) in registers (16 lanes x float4/node), then
// HL = h@W2l^T, HR = h@W2r^T + b2l via in-group shfl_xor dot-reduce.
// Gather unrolled 8x (round-8: 60us, VALUBusy 19%, occ 60% -> MLP-limited).
__global__ __launch_bounds__(256) void k_agg1g2(const int* __restrict__ rs, const int* __restrict__ re,
                                                const int* __restrict__ csr_src,
                                                const float* __restrict__ XL, const float* __restrict__ XR,
                                                const float* __restrict__ W2l, const float* __restrict__ b2l,
                                                const float* __restrict__ W2r,
                                                float* __restrict__ HL, float* __restrict__ HR,
                                                int n_nodes) {
  int wave = threadIdx.x >> 6, lane = threadIdx.x & 63;
  int g = lane >> 4, c = lane & 15;
  int n = (blockIdx.x * 4 + wave) * 4 + g;
  if (n >= n_nodes) return;

  float4 wl0 = *(const float4*)(W2l + c * 4);
  float4 wl1 = *(const float4*)(W2l + 64 + c * 4);
  float4 wr0 = *(const float4*)(W2r + c * 4);
  float4 wr1 = *(const float4*)(W2r + 64 + c * 4);
  float4 xr = *(const float4*)(XR + (size_t)n * 64 + c * 4);

  int start = rs[n], end = re[n];
  float4 a0 = make_float4(0.f, 0.f, 0.f, 0.f);
  float4 a1 = make_float4(0.f, 0.f, 0.f, 0.f);
  float4 a2 = make_float4(0.f, 0.f, 0.f, 0.f);
  float4 a3 = make_float4(0.f, 0.f, 0.f, 0.f);
  int e = start;
  for (; e + 7 < end; e += 8) {               // unroll-8: 8 outstanding reads
    int s0 = csr_src[e],     s1 = csr_src[e + 1], s2 = csr_src[e + 2], s3 = csr_src[e + 3];
    int s4 = csr_src[e + 4], s5 = csr_src[e + 5], s6 = csr_src[e + 6], s7 = csr_src[e + 7];
    float4 v0 = *(const float4*)(XL + (size_t)s0 * 64 + c * 4);
    float4 v1 = *(const float4*)(XL + (size_t)s1 * 64 + c * 4);
    float4 v2 = *(const float4*)(XL + (size_t)s2 * 64 + c * 4);
    float4 v3 = *(const float4*)(XL + (size_t)s3 * 64 + c * 4);
    float4 v4 = *(const float4*)(XL + (size_t)s4 * 64 + c * 4);
    float4 v5 = *(const float4*)(XL + (size_t)s5 * 64 + c * 4);
    float4 v6 = *(const float4*)(XL + (size_t)s6 * 64 + c * 4);
    float4 v7 = *(const float4*)(XL + (size_t)s7 * 64 + c * 4);
    a0.x += v0.x; a0.y += v0.y; a0.z += v0.z; a0.w += v0.w;
    a1.x += v1.x; a1.y += v1.y; a1.z += v1.z; a1.w += v1.w;
    a2.x += v2.x; a2.y += v2.y; a2.z += v2.z; a2.w += v2.w;
    a3.x += v3.x; a3.y += v3.y; a3.z += v3.z; a3.w += v3.w;
    a0.x += v4.x; a0.y += v4.y; a0.z += v4.z; a0.w += v4.w;
    a1.x += v5.x; a1.y += v5.y; a1.z += v5.z; a1.w += v5.w;
    a2.x += v6.x; a2.y += v6.y; a2.z += v6.z; a2.w += v6.w;
    a3.x += v7.x; a3.y += v7.y; a3.z += v7.z; a3.w += v7.w;
  }
  for (; e + 3 < end; e += 4) {
    int s0 = csr_src[e], s1 = csr_src[e + 1], s2 = csr_src[e + 2], s3 = csr_src[e + 3];
    float4 v0 = *(const float4*)(XL + (size_t)s0 * 64 + c * 4);
    float4 v1 = *(const float4*)(XL + (size_t)s1 * 64 + c * 4);
    float4 v2 = *(const float4*)(XL + (size_t)s2 * 64 + c * 4);
    float4 v3 = *(const float4*)(XL + (size_t)s3 * 64 + c * 4);
    a0.x += v0.x; a0.y += v0.y; a0.z += v0.z; a0.w += v0.w;
    a1.x += v1.x; a1.y += v1.y; a1.z += v1.z; a1.w += v1.w;
    a2.x += v2.x; a2.y += v2.y; a2.z += v2.z; a2.w += v2.w;
    a3.x += v3.x; a3.y += v3.y; a3.z += v3.z; a3.w += v3.w;
  }
  if (e + 1 < end) {
    int s0 = csr_src[e], s1 = csr_src[e + 1];
    float4 v0 = *(const float4*)(XL + (size_t)s0 * 64 + c * 4);
    float4 v1 = *(const float4*)(XL + (size_t)s1 * 64 + c * 4);
    a0.x += v0.x; a0.y += v0.y; a0.z += v0.z; a0.w += v0.w;
    a1.x += v1.x; a1.y += v1.y; a1.z += v1.z; a1.w += v1.w;
    e += 2;
  }
  if (e < end) {
    int s0 = csr_src[e];
    float4 v0 = *(const float4*)(XL + (size_t)s0 * 64 + c * 4);
    a0.x += v0.x; a0.y += v0.y; a0.z += v0.z; a0.w += v0.w;
  }
  float inv = 1.0f / fmaxf((float)(end - start), 1.0f);
  float4 h;
  h.x = fmaxf((a0.x + a1.x + a2.x + a3.x) * inv + xr.x, 0.f);
  h.y = fmaxf((a0.y + a1.y + a2.y + a3.y) * inv + xr.y, 0.f);
  h.z = fmaxf((a0.z + a1.z + a2.z + a3.z) * inv + xr.z, 0.f);
  h.w = fmaxf((a0.w + a1.w + a2.w + a3.w) * inv + xr.w, 0.f);

  float p0 = h.x * wl0.x + h.y * wl0.y + h.z * wl0.z + h.w * wl0.w;
  float p1 = h.x * wl1.x + h.y * wl1.y + h.z * wl1.z + h.w * wl1.w;
  float q0 = h.x * wr0.x + h.y * wr0.y + h.z * wr0.z + h.w * wr0.w;
  float q1 = h.x * wr1.x + h.y * wr1.y + h.z * wr1.z + h.w * wr1.w;
#pragma unroll
  for (int off = 1; off < 16; off <<= 1) {
    p0 += __shfl_xor(p0, off, 16);
    p1 += __shfl_xor(p1, off, 16);
    q0 += __shfl_xor(q0, off, 16);
    q1 += __shfl_xor(q1, off, 16);
  }
  if (c == 0) {
    *(float2*)(HL + (size_t)n * 2) = make_float2(p0, p1);
    *(float2*)(HR + (size_t)n * 2) = make_float2(q0 + b2l[0], q1 + b2l[1]);
  }
}

// --- AGG2: out = mean_j HL[j] + HR  (thread per node, 2-dim features) ------
__global__ __launch_bounds__(256) void k_agg2(const int* __restrict__ rs, const int* __restrict__ re,
                                              const int* __restrict__ csr_src,
                                              const float* __restrict__ HL, const float* __restrict__ HR,
                                              float* __restrict__ out, int n_nodes) {
  int n = blockIdx.x * 256 + threadIdx.x;
  if (n >= n_nodes) return;
  int start = rs[n], end = re[n];
  float s0 = 0.f, s1 = 0.f;
  int e = start;
  for (; e + 1 < end; e += 2) {
    int sa = csr_src[e], sb = csr_src[e + 1];
    float2 va = *(const float2*)(HL + (size_t)sa * 2);
    float2 vb = *(const float2*)(HL + (size_t)sb * 2);
    s0 += va.x + vb.x; s1 += va.y + vb.y;
  }
  if (e < end) {
    int sa = csr_src[e];
    float2 va = *(const float2*)(HL + (size_t)sa * 2);
    s0 += va.x; s1 += va.y;
  }
  float inv = 1.0f / fmaxf((float)(end - start), 1.0f);
  float2 hr = *(const float2*)(HR + (size_t)n * 2);
  out[n * 2 + 0] = s0 * inv + hr.x;
  out[n * 2 + 1] = s1 * inv + hr.y;
}

// ---------------------------------------------------------------------------
extern "C" void kernel_launch(void* const* d_in, const int* in_sizes, int n_in,
                              void* d_out, int out_size, void* d_ws, size_t ws_size,
                              hipStream_t stream) {
  const float* x   = (const float*)d_in[0];
  const void*  eix = d_in[1];
  const float* W1l = (const float*)d_in[2];
  const float* b1l = (const float*)d_in[3];
  const float* W1r = (const float*)d_in[4];
  const float* W2l = (const float*)d_in[5];
  const float* b2l = (const float*)d_in[6];
  const float* W2r = (const float*)d_in[7];
  float* out = (float*)d_out;

  const int N = in_sizes[0] / 64;        // 100000
  const int E = in_sizes[1] / 2;         // 1600000
  const int NB = (N + 255) >> BKT_SHIFT; // 391 buckets

  // workspace layout (256B-aligned chunks)
  char* base = (char*)d_ws;
  size_t off = 0;
  auto alloc = [&](size_t bytes) {
    char* p = base + off;
    off = (off + bytes + 255) & ~(size_t)255;
    return p;
  };
  int*   gcount  = (int*)alloc((size_t)BKT_MAX * 4);
  int*   rs      = (int*)alloc((size_t)N * 4);
  int*   re      = (int*)alloc((size_t)N * 4);
  int*   csr_src = (int*)alloc((size_t)NB * BKT_CAP * 4);   // 8.0 MB
  u32*   pairs   = (u32*)alloc((size_t)NB * BKT_CAP * 4);   // 8.0 MB (no alias:
  float* XL      = (float*)alloc((size_t)N * 64 * 4);       //  XL written concurrently)
  float* XR      = (float*)alloc((size_t)N * 64 * 4);
  float* HL      = (float*)alloc((size_t)N * 2 * 4);
  float* HR      = (float*)alloc((size_t)N * 2 * 4);
  (void)ws_size;

  const int nbkt = (E + CHUNK - 1) / CHUNK;       // 782 bucket blocks
  const int ngem = (N + 63) / 64;                 // 1563 gemm blocks

  hipMemsetAsync(gcount, 0, (size_t)BKT_MAX * 4, stream);
  k_pre<<<nbkt + ngem, 256, 0, stream>>>(eix, gcount, pairs, E,
                                         x, W1l, b1l, W1r, XL, XR, N, nbkt);
  k_csr<<<NB, 512, 0, stream>>>(gcount, pairs, csr_src, rs, re, N);
  k_agg1g2<<<(N + 15) / 16, 256, 0, stream>>>(rs, re, csr_src, XL, XR, W2l, b2l, W2r, HL, HR, N);
  k_agg2<<<(N + 255) / 256, 256, 0, stream>>>(rs, re, csr_src, HL, HR, out, N);
}

// Round 10
// 202.181 us; speedup vs baseline: 1.9006x; 1.0851x over previous
//
#include <hip/hip_runtime.h>
#include <cstdint>

typedef long long i64;
typedef unsigned int u32;

// ---------------------------------------------------------------------------
// FraudGNN: 2-layer GraphSAGE (mean aggr), N=100K, E=1.6M, d 64->64->2, fp32.
// Rewrite: lin(mean(x)) == mean(lin(x))  -> transform first, aggregate after.
//   XL = x@W1l^T ; XR = x@W1r^T + b1l
//   h  = relu(meanagg(XL) + XR)            (registers only, never stored)
//   HL = h@W2l^T ; HR = h@W2r^T + b2l      (fused into the aggregation kernel)
//   out = meanagg(HL) + HR                 (2-dim gather, L2-resident)
//
// CSR build: fixed-capacity bucketed counting sort, zero per-edge global
// atomics. History: r3 global scatter 138us/105MB wr; r4 global atomic hist
// 71us/50MB RMW; r7 CHUNK=16384 3.8%occ 60us; r9 fused-but-phase-separated
// k_pre 65us w/ 78MB writes (1.6M scattered 4B stores = 1.6M line txns).
//
// Round-10: (a) roles interleaved blockIdx%5 (1 bucket : 4 gemm) so bucket
// (latency-bound) and GEMM1 (VALU-bound) truly co-reside per CU; (b) pass-A
// does an in-LDS counting sort per 4096-edge chunk: hist -> 2-level scan ->
// LDS scatter of (gpos,val) -> linear writeout; consecutive lanes write
// consecutive global addrs within each run -> coalesced stores, ~6x fewer
// line transactions.
// ---------------------------------------------------------------------------

#define BKT_SHIFT 8          // 256 nodes per bucket
#define BKT_MAX   512        // LDS array size (NB=391 for N=100000)
#define BKT_CAP   5120       // slots per bucket (mean 4096 +16 sigma)
#define CHUNK     4096       // edges per bucket block
#define EPT       16         // edges staged per thread (256 thr * 16 = 4096)

__device__ __forceinline__ int edge_at(const void* eidx, int is64, size_t i) {
  return is64 ? (int)((const i64*)eidx)[i] : ((const int*)eidx)[i];
}

// --- k_pre: interleaved heterogeneous blocks: blockIdx%5==0 -> bucket pass-A,
//            else GEMM1. grid = 5*nbkt (nbkt=391, ngem=1563 = 4*nbkt).
__global__ __launch_bounds__(256) void k_pre(const void* __restrict__ eidx,
                                             int* __restrict__ gcount, u32* __restrict__ pairs, int E,
                                             const float* __restrict__ x,
                                             const float* __restrict__ Wl, const float* __restrict__ bl,
                                             const float* __restrict__ Wr,
                                             float* __restrict__ XL, float* __restrict__ XR,
                                             int n_nodes, int nbkt, int ngem) {
  __shared__ float smem[64 * 68 * 3];          // 52224B, shared by both roles
  int tid = threadIdx.x;
  int bid = blockIdx.x;

  if (bid % 5 == 0) {
    // ---------------- bucket pass-A: in-LDS counting sort ----------------
    int b5 = bid / 5;                          // 0..nbkt-1
    int* hist  = (int*)smem;                   // [BKT_MAX]
    int* lbase = hist + BKT_MAX;               // [BKT_MAX] LDS run base
    int* gbase = lbase + BKT_MAX;              // [BKT_MAX] global run base
    int* run   = gbase + BKT_MAX;              // [BKT_MAX]
    int* nzp   = run + BKT_MAX;                // [1]
    u32* sg    = (u32*)(nzp + 1);              // [CHUNK] gpos per sorted slot
    u32* sv    = sg + CHUNK;                   // [CHUNK] packed val per slot
    for (int i = tid; i < BKT_MAX; i += 256) { hist[i] = 0; run[i] = 0; }
    if (tid == 0) *nzp = 0;
    __syncthreads();
    // inline dtype probe: int64 layout => odd 32-bit words all zero
    if (((const int*)eidx)[2 * tid + 1] != 0) *nzp = 1;
    __syncthreads();
    int is64 = (*nzp == 0);

    int cbase = b5 * CHUNK;
    int sreg[EPT], dreg[EPT];
#pragma unroll
    for (int i = 0; i < EPT; ++i) {            // stage 16 edges/thread in regs
      int e = cbase + tid + 256 * i;
      bool v = e < E;
      sreg[i] = v ? edge_at(eidx, is64, (size_t)e) : 0;
      dreg[i] = v ? edge_at(eidx, is64, (size_t)E + e) : -1;
      if (v) atomicAdd(&hist[dreg[i] >> BKT_SHIFT], 1);
    }
    __syncthreads();
    // 2-level exclusive scan over 512 buckets (each thread owns 2); scratch
    // lives in sv[0..255] (free until the scatter below).
    int h0 = hist[2 * tid], h1 = hist[2 * tid + 1];
    int ps = h0 + h1;
    int* sc = (int*)sv;
    sc[tid] = ps;
    __syncthreads();
    for (int off = 1; off < 256; off <<= 1) {
      int a = (tid >= off) ? sc[tid - off] : 0;
      __syncthreads();
      sc[tid] += a;
      __syncthreads();
    }
    int excl = sc[tid] - ps;
    lbase[2 * tid]     = excl;
    lbase[2 * tid + 1] = excl + h0;
    // reserve global runs (one atomic per non-empty bucket per chunk)
    gbase[2 * tid]     = h0 ? (2 * tid) * BKT_CAP + atomicAdd(&gcount[2 * tid], h0) : 0;
    gbase[2 * tid + 1] = h1 ? (2 * tid + 1) * BKT_CAP + atomicAdd(&gcount[2 * tid + 1], h1) : 0;
    __syncthreads();                           // sc reads done; sv reusable
    // LDS scatter into bucket-sorted order
#pragma unroll
    for (int i = 0; i < EPT; ++i) {
      if (dreg[i] >= 0) {
        int b = dreg[i] >> BKT_SHIFT;
        int r = atomicAdd(&run[b], 1);
        int p = lbase[b] + r;
        sg[p] = gbase[b] + r;
        sv[p] = ((u32)sreg[i] << 8) | (u32)(dreg[i] & 255);
      }
    }
    __syncthreads();
    // linear writeout: consecutive lanes -> consecutive gpos within runs
    int total = min(E - cbase, CHUNK);
    for (int i = tid; i < total; i += 256)
      pairs[sg[i]] = sv[i];
    return;
  }

  // ---------------- GEMM1: XL = x@Wl^T, XR = x@Wr^T + bl ----------------
  int g = bid - bid / 5 - 1;                   // gemm ordinal (bid%5 != 0)
  if (g >= ngem) return;
  // stride 68 floats: float4-aligned, 2-way bank aliasing (free per m136)
  float* sWl = smem;                           // [64*68]
  float* sWr = smem + 64 * 68;
  float* sX  = smem + 2 * 64 * 68;
  int base = g * 64;

#pragma unroll
  for (int r = 0; r < 4; ++r) {                // weights: 64f x 16 float4
    int idx = tid + 256 * r;
    int f = idx >> 4, c4 = idx & 15;
    float4 wl = *(const float4*)(Wl + f * 64 + c4 * 4);
    float4 wr = *(const float4*)(Wr + f * 64 + c4 * 4);
    sWl[(c4 * 4 + 0) * 68 + f] = wl.x; sWl[(c4 * 4 + 1) * 68 + f] = wl.y;
    sWl[(c4 * 4 + 2) * 68 + f] = wl.z; sWl[(c4 * 4 + 3) * 68 + f] = wl.w;
    sWr[(c4 * 4 + 0) * 68 + f] = wr.x; sWr[(c4 * 4 + 1) * 68 + f] = wr.y;
    sWr[(c4 * 4 + 2) * 68 + f] = wr.z; sWr[(c4 * 4 + 3) * 68 + f] = wr.w;
  }
#pragma unroll
  for (int r = 0; r < 4; ++r) {                // x tile: 64n x 16 float4
    int idx = tid + 256 * r;
    int nn = idx >> 4, c4 = idx & 15;
    int node = base + nn;
    float4 xv = make_float4(0.f, 0.f, 0.f, 0.f);
    if (node < n_nodes) xv = *(const float4*)(x + (size_t)node * 64 + c4 * 4);
    sX[(c4 * 4 + 0) * 68 + nn] = xv.x; sX[(c4 * 4 + 1) * 68 + nn] = xv.y;
    sX[(c4 * 4 + 2) * 68 + nn] = xv.z; sX[(c4 * 4 + 3) * 68 + nn] = xv.w;
  }
  __syncthreads();

  int f0 = (tid & 15) * 4, n0 = (tid >> 4) * 4;
  float accL[4][4] = {{0}}, accR[4][4] = {{0}};
#pragma unroll 8
  for (int k = 0; k < 64; ++k) {
    float4 xv = *(const float4*)&sX[k * 68 + n0];
    float4 wl = *(const float4*)&sWl[k * 68 + f0];
    float4 wr = *(const float4*)&sWr[k * 68 + f0];
    float xn[4] = {xv.x, xv.y, xv.z, xv.w};
    float wlf[4] = {wl.x, wl.y, wl.z, wl.w};
    float wrf[4] = {wr.x, wr.y, wr.z, wr.w};
#pragma unroll
    for (int a = 0; a < 4; ++a)
#pragma unroll
      for (int b = 0; b < 4; ++b) {
        accL[a][b] += xn[a] * wlf[b];
        accR[a][b] += xn[a] * wrf[b];
      }
  }

  float4 blv = *(const float4*)(bl + f0);
#pragma unroll
  for (int a = 0; a < 4; ++a) {
    int node = base + n0 + a;
    if (node >= n_nodes) continue;
    float4 ol = make_float4(accL[a][0], accL[a][1], accL[a][2], accL[a][3]);
    float4 orr = make_float4(accR[a][0] + blv.x, accR[a][1] + blv.y,
                             accR[a][2] + blv.z, accR[a][3] + blv.w);
    *(float4*)(XL + (size_t)node * 64 + f0) = ol;
    *(float4*)(XR + (size_t)node * 64 + f0) = orr;
  }
}

// --- pass B: one workgroup (512 thr) owns one bucket -----------------------
// count -> LDS scan (recovers row_ptr for free) -> single-writer scatter.
__global__ __launch_bounds__(512) void k_csr(const int* __restrict__ gcount, const u32* __restrict__ pairs,
                                             int* __restrict__ csr_src, int* __restrict__ rs,
                                             int* __restrict__ re, int n_nodes) {
  __shared__ int cnt[256];
  __shared__ int sc[256];
  __shared__ int cur[256];
  int b = blockIdx.x, t = threadIdx.x;
  if (t < 256) cnt[t] = 0;
  __syncthreads();
  int n = gcount[b];
  int lo = b * BKT_CAP, hi = lo + n;
  int tail = n & 3;
  for (int i = lo + t * 4; i + 3 < hi; i += 2048) {     // uint4: 4 pairs/iter
    uint4 p = *(const uint4*)(pairs + i);
    atomicAdd(&cnt[p.x & 255], 1); atomicAdd(&cnt[p.y & 255], 1);
    atomicAdd(&cnt[p.z & 255], 1); atomicAdd(&cnt[p.w & 255], 1);
  }
  if (t < tail) atomicAdd(&cnt[pairs[hi - tail + t] & 255], 1);
  __syncthreads();
  int v = (t < 256) ? cnt[t] : 0;
  if (t < 256) sc[t] = v;
  __syncthreads();
  for (int off = 1; off < 256; off <<= 1) {
    int a = (t >= off && t < 256) ? sc[t - off] : 0;
    __syncthreads();
    if (t < 256) sc[t] += a;
    __syncthreads();
  }
  if (t < 256) {
    int start = lo + sc[t] - v;          // bucket-private exclusive scan
    int node = (b << BKT_SHIFT) + t;
    if (node < n_nodes) { rs[node] = start; re[node] = start + v; }
    cur[t] = start;
  }
  __syncthreads();
  for (int i = lo + t * 4; i + 3 < hi; i += 2048) {
    uint4 p = *(const uint4*)(pairs + i);
    csr_src[atomicAdd(&cur[p.x & 255], 1)] = (int)(p.x >> 8);
    csr_src[atomicAdd(&cur[p.y & 255], 1)] = (int)(p.y >> 8);
    csr_src[atomicAdd(&cur[p.z & 255], 1)] = (int)(p.z >> 8);
    csr_src[atomicAdd(&cur[p.w & 255], 1)] = (int)(p.w >> 8);
  }
  if (t < tail) {
    u32 p = pairs[hi - tail + t];
    csr_src[atomicAdd(&cur[p & 255], 1)] = (int)(p >> 8);
  }
}

// --- AGG1 + GEMM2 fused ----------------------------------------------------
// h = relu(mean_j XL[j] + XR) in registers (16 lanes x float4/node), then
// HL = h@W2l^T, HR = h@W2r^T + b2l via in-group shfl_xor dot-reduce.
__global__ __launch_bounds__(256) void k_agg1g2(const int* __restrict__ rs, const int* __restrict__ re,
                                                const int* __restrict__ csr_src,
                                                const float* __restrict__ XL, const float* __restrict__ XR,
                                                const float* __restrict__ W2l, const float* __restrict__ b2l,
                                                const float* __restrict__ W2r,
                                                float* __restrict__ HL, float* __restrict__ HR,
                                                int n_nodes) {
  int wave = threadIdx.x >> 6, lane = threadIdx.x & 63;
  int g = lane >> 4, c = lane & 15;
  int n = (blockIdx.x * 4 + wave) * 4 + g;
  if (n >= n_nodes) return;

  float4 wl0 = *(const float4*)(W2l + c * 4);
  float4 wl1 = *(const float4*)(W2l + 64 + c * 4);
  float4 wr0 = *(const float4*)(W2r + c * 4);
  float4 wr1 = *(const float4*)(W2r + 64 + c * 4);
  float4 xr = *(const float4*)(XR + (size_t)n * 64 + c * 4);

  int start = rs[n], end = re[n];
  float4 a0 = make_float4(0.f, 0.f, 0.f, 0.f);
  float4 a1 = make_float4(0.f, 0.f, 0.f, 0.f);
  float4 a2 = make_float4(0.f, 0.f, 0.f, 0.f);
  float4 a3 = make_float4(0.f, 0.f, 0.f, 0.f);
  int e = start;
  for (; e + 7 < end; e += 8) {               // unroll-8: 8 outstanding reads
    int s0 = csr_src[e],     s1 = csr_src[e + 1], s2 = csr_src[e + 2], s3 = csr_src[e + 3];
    int s4 = csr_src[e + 4], s5 = csr_src[e + 5], s6 = csr_src[e + 6], s7 = csr_src[e + 7];
    float4 v0 = *(const float4*)(XL + (size_t)s0 * 64 + c * 4);
    float4 v1 = *(const float4*)(XL + (size_t)s1 * 64 + c * 4);
    float4 v2 = *(const float4*)(XL + (size_t)s2 * 64 + c * 4);
    float4 v3 = *(const float4*)(XL + (size_t)s3 * 64 + c * 4);
    float4 v4 = *(const float4*)(XL + (size_t)s4 * 64 + c * 4);
    float4 v5 = *(const float4*)(XL + (size_t)s5 * 64 + c * 4);
    float4 v6 = *(const float4*)(XL + (size_t)s6 * 64 + c * 4);
    float4 v7 = *(const float4*)(XL + (size_t)s7 * 64 + c * 4);
    a0.x += v0.x; a0.y += v0.y; a0.z += v0.z; a0.w += v0.w;
    a1.x += v1.x; a1.y += v1.y; a1.z += v1.z; a1.w += v1.w;
    a2.x += v2.x; a2.y += v2.y; a2.z += v2.z; a2.w += v2.w;
    a3.x += v3.x; a3.y += v3.y; a3.z += v3.z; a3.w += v3.w;
    a0.x += v4.x; a0.y += v4.y; a0.z += v4.z; a0.w += v4.w;
    a1.x += v5.x; a1.y += v5.y; a1.z += v5.z; a1.w += v5.w;
    a2.x += v6.x; a2.y += v6.y; a2.z += v6.z; a2.w += v6.w;
    a3.x += v7.x; a3.y += v7.y; a3.z += v7.z; a3.w += v7.w;
  }
  for (; e + 3 < end; e += 4) {
    int s0 = csr_src[e], s1 = csr_src[e + 1], s2 = csr_src[e + 2], s3 = csr_src[e + 3];
    float4 v0 = *(const float4*)(XL + (size_t)s0 * 64 + c * 4);
    float4 v1 = *(const float4*)(XL + (size_t)s1 * 64 + c * 4);
    float4 v2 = *(const float4*)(XL + (size_t)s2 * 64 + c * 4);
    float4 v3 = *(const float4*)(XL + (size_t)s3 * 64 + c * 4);
    a0.x += v0.x; a0.y += v0.y; a0.z += v0.z; a0.w += v0.w;
    a1.x += v1.x; a1.y += v1.y; a1.z += v1.z; a1.w += v1.w;
    a2.x += v2.x; a2.y += v2.y; a2.z += v2.z; a2.w += v2.w;
    a3.x += v3.x; a3.y += v3.y; a3.z += v3.z; a3.w += v3.w;
  }
  if (e + 1 < end) {
    int s0 = csr_src[e], s1 = csr_src[e + 1];
    float4 v0 = *(const float4*)(XL + (size_t)s0 * 64 + c * 4);
    float4 v1 = *(const float4*)(XL + (size_t)s1 * 64 + c * 4);
    a0.x += v0.x; a0.y += v0.y; a0.z += v0.z; a0.w += v0.w;
    a1.x += v1.x; a1.y += v1.y; a1.z += v1.z; a1.w += v1.w;
    e += 2;
  }
  if (e < end) {
    int s0 = csr_src[e];
    float4 v0 = *(const float4*)(XL + (size_t)s0 * 64 + c * 4);
    a0.x += v0.x; a0.y += v0.y; a0.z += v0.z; a0.w += v0.w;
  }
  float inv = 1.0f / fmaxf((float)(end - start), 1.0f);
  float4 h;
  h.x = fmaxf((a0.x + a1.x + a2.x + a3.x) * inv + xr.x, 0.f);
  h.y = fmaxf((a0.y + a1.y + a2.y + a3.y) * inv + xr.y, 0.f);
  h.z = fmaxf((a0.z + a1.z + a2.z + a3.z) * inv + xr.z, 0.f);
  h.w = fmaxf((a0.w + a1.w + a2.w + a3.w) * inv + xr.w, 0.f);

  float p0 = h.x * wl0.x + h.y * wl0.y + h.z * wl0.z + h.w * wl0.w;
  float p1 = h.x * wl1.x + h.y * wl1.y + h.z * wl1.z + h.w * wl1.w;
  float q0 = h.x * wr0.x + h.y * wr0.y + h.z * wr0.z + h.w * wr0.w;
  float q1 = h.x * wr1.x + h.y * wr1.y + h.z * wr1.z + h.w * wr1.w;
#pragma unroll
  for (int off = 1; off < 16; off <<= 1) {
    p0 += __shfl_xor(p0, off, 16);
    p1 += __shfl_xor(p1, off, 16);
    q0 += __shfl_xor(q0, off, 16);
    q1 += __shfl_xor(q1, off, 16);
  }
  if (c == 0) {
    *(float2*)(HL + (size_t)n * 2) = make_float2(p0, p1);
    *(float2*)(HR + (size_t)n * 2) = make_float2(q0 + b2l[0], q1 + b2l[1]);
  }
}

// --- AGG2: out = mean_j HL[j] + HR  (thread per node, 2-dim features) ------
__global__ __launch_bounds__(256) void k_agg2(const int* __restrict__ rs, const int* __restrict__ re,
                                              const int* __restrict__ csr_src,
                                              const float* __restrict__ HL, const float* __restrict__ HR,
                                              float* __restrict__ out, int n_nodes) {
  int n = blockIdx.x * 256 + threadIdx.x;
  if (n >= n_nodes) return;
  int start = rs[n], end = re[n];
  float s0 = 0.f, s1 = 0.f;
  int e = start;
  for (; e + 1 < end; e += 2) {
    int sa = csr_src[e], sb = csr_src[e + 1];
    float2 va = *(const float2*)(HL + (size_t)sa * 2);
    float2 vb = *(const float2*)(HL + (size_t)sb * 2);
    s0 += va.x + vb.x; s1 += va.y + vb.y;
  }
  if (e < end) {
    int sa = csr_src[e];
    float2 va = *(const float2*)(HL + (size_t)sa * 2);
    s0 += va.x; s1 += va.y;
  }
  float inv = 1.0f / fmaxf((float)(end - start), 1.0f);
  float2 hr = *(const float2*)(HR + (size_t)n * 2);
  out[n * 2 + 0] = s0 * inv + hr.x;
  out[n * 2 + 1] = s1 * inv + hr.y;
}

// ---------------------------------------------------------------------------
extern "C" void kernel_launch(void* const* d_in, const int* in_sizes, int n_in,
                              void* d_out, int out_size, void* d_ws, size_t ws_size,
                              hipStream_t stream) {
  const float* x   = (const float*)d_in[0];
  const void*  eix = d_in[1];
  const float* W1l = (const float*)d_in[2];
  const float* b1l = (const float*)d_in[3];
  const float* W1r = (const float*)d_in[4];
  const float* W2l = (const float*)d_in[5];
  const float* b2l = (const float*)d_in[6];
  const float* W2r = (const float*)d_in[7];
  float* out = (float*)d_out;

  const int N = in_sizes[0] / 64;        // 100000
  const int E = in_sizes[1] / 2;         // 1600000
  const int NB = (N + 255) >> BKT_SHIFT; // 391 buckets

  // workspace layout (256B-aligned chunks)
  char* base = (char*)d_ws;
  size_t off = 0;
  auto alloc = [&](size_t bytes) {
    char* p = base + off;
    off = (off + bytes + 255) & ~(size_t)255;
    return p;
  };
  int*   gcount  = (int*)alloc((size_t)BKT_MAX * 4);
  int*   rs      = (int*)alloc((size_t)N * 4);
  int*   re      = (int*)alloc((size_t)N * 4);
  int*   csr_src = (int*)alloc((size_t)NB * BKT_CAP * 4);   // 8.0 MB
  u32*   pairs   = (u32*)alloc((size_t)NB * BKT_CAP * 4);   // 8.0 MB (no alias:
  float* XL      = (float*)alloc((size_t)N * 64 * 4);       //  XL written concurrently)
  float* XR      = (float*)alloc((size_t)N * 64 * 4);
  float* HL      = (float*)alloc((size_t)N * 2 * 4);
  float* HR      = (float*)alloc((size_t)N * 2 * 4);
  (void)ws_size;

  const int nbkt = (E + CHUNK - 1) / CHUNK;       // 391 bucket blocks
  const int ngem = (N + 63) / 64;                 // 1563 gemm blocks

  hipMemsetAsync(gcount, 0, (size_t)BKT_MAX * 4, stream);
  k_pre<<<5 * nbkt, 256, 0, stream>>>(eix, gcount, pairs, E,
                                      x, W1l, b1l, W1r, XL, XR, N, nbkt, ngem);
  k_csr<<<NB, 512, 0, stream>>>(gcount, pairs, csr_src, rs, re, N);
  k_agg1g2<<<(N + 15) / 16, 256, 0, stream>>>(rs, re, csr_src, XL, XR, W2l, b2l, W2r, HL, HR, N);
  k_agg2<<<(N + 255) / 256, 256, 0, stream>>>(rs, re, csr_src, HL, HR, out, N);
}